// Round 12
// baseline (304.622 us; speedup 1.0000x reference)
//
#include <hip/hip_runtime.h>
#include <math.h>

constexpr int Bsz = 4, Lseq = 1024, Dmodel = 512, NLAYERS = 2;
constexpr int DI = 1024, NST = 16, RNK = 32;
constexpr int BLQ = Bsz * Lseq;     // 4096 rows
constexpr int NCH = 32, CLEN = 32;  // chunked scan

typedef __attribute__((ext_vector_type(8))) short short8v;
typedef __attribute__((ext_vector_type(8))) unsigned short ushort8v;
typedef __attribute__((ext_vector_type(4))) float f32x4;
typedef unsigned short ushort;

__device__ inline ushort bf16_rne(float v) {
  unsigned u = __float_as_uint(v);
  u += 0x7FFFu + ((u >> 16) & 1u);
  return (ushort)(u >> 16);
}
__device__ inline float bf2f(ushort u) {
  return __uint_as_float(((unsigned)u) << 16);
}
// fragment address for element (row, k); chunk per (rt,kt): [kk(2)][msub(8)][lane(64)][8]
__device__ inline size_t frag_off(int row, int k, int KT) {
  int kt = k >> 6, kk = (k >> 5) & 1, k8 = (k >> 3) & 3;
  int lanei = (row & 15) | (k8 << 4), msub = (row >> 4) & 7, rt = row >> 7;
  return ((((size_t)(rt * KT + kt) * 2 + kk) * 8 + msub) * 64 + lanei) * 8;
}
#define GLDS(gp, lp) __builtin_amdgcn_global_load_lds( \
    (const __attribute__((address_space(1))) void*)(gp), \
    (__attribute__((address_space(3))) void*)(lp), 16, 0, 0)

// ------- embed gather + ALL weights -> bf16 fragments, one kernel ------------
// blocks: [0,1024) embed; [1024,2048) in_w; [2048,2112) xp_w; [2112,2624) out_w
__global__ __launch_bounds__(256) void embcvt_kernel(
    const int* __restrict__ x, const float* __restrict__ emb,
    const float* __restrict__ in_w, const float* __restrict__ xp_w,
    const float* __restrict__ out_w,
    ushort* __restrict__ Af,
    ushort* __restrict__ WIh, ushort* __restrict__ WIl,
    ushort* __restrict__ XPh, ushort* __restrict__ XPl,
    ushort* __restrict__ WOh)
{
  int blk = blockIdx.x;
  if (blk < 1024) {                       // embedding -> A fragments (K=512)
    int i = blk * 256 + threadIdx.x;
    int row = i >> 6, k = (i & 63) * 8;
    int tok = x[row];
    const float* src = &emb[(size_t)tok * Dmodel + k];
    float4 v0 = *reinterpret_cast<const float4*>(src);
    float4 v1 = *reinterpret_cast<const float4*>(src + 4);
    float xs[8] = {v0.x, v0.y, v0.z, v0.w, v1.x, v1.y, v1.z, v1.w};
    ushort hv[8];
#pragma unroll
    for (int e = 0; e < 8; ++e) hv[e] = bf16_rne(xs[e]);
    *reinterpret_cast<ushort8v*>(&Af[frag_off(row, k, 8)]) =
        *reinterpret_cast<ushort8v*>(hv);
    return;
  }
  const float* src; ushort *dh, *dl; size_t doff; bool wantlo = true;
  if (blk < 2048) {                       // in_w (split)
    int u = (blk - 1024) * 256 + threadIdx.x;
    int l = u >> 17, rem = u & 131071;
    int row = rem >> 6, k = (rem & 63) * 8;
    src = in_w + (size_t)l * 2048 * 512 + (size_t)row * 512 + k;
    size_t base = (size_t)l * 2048 * 512;
    dh = WIh + base; dl = WIl + base; doff = frag_off(row, k, 8);
  } else if (blk < 2112) {                // xp_w (split; 128-row padded chunks)
    int u = (blk - 2048) * 256 + threadIdx.x;
    int l = u >> 13, rem = u & 8191;
    int row = rem >> 7, k = (rem & 127) * 8;
    src = xp_w + (size_t)l * 64 * 1024 + (size_t)row * 1024 + k;
    size_t base = (size_t)l * 131072;
    dh = XPh + base; dl = XPl + base; doff = frag_off(row, k, 16);
  } else {                                // out_w (hi only)
    int u = (blk - 2112) * 256 + threadIdx.x;
    int l = u >> 16, rem = u & 65535;
    int row = rem >> 7, k = (rem & 127) * 8;
    src = out_w + (size_t)l * 512 * 1024 + (size_t)row * 1024 + k;
    size_t base = (size_t)l * 512 * 1024;
    dh = WOh + base; dl = nullptr; doff = frag_off(row, k, 16); wantlo = false;
  }
  float4 v0 = *reinterpret_cast<const float4*>(src);
  float4 v1 = *reinterpret_cast<const float4*>(src + 4);
  float xs[8] = {v0.x, v0.y, v0.z, v0.w, v1.x, v1.y, v1.z, v1.w};
  ushort hs[8], ls[8];
#pragma unroll
  for (int j = 0; j < 8; ++j) {
    unsigned u = __float_as_uint(xs[j]);
    float hf = __uint_as_float(u & 0xFFFF0000u);
    float r = xs[j] - hf;
    hs[j] = (ushort)(u >> 16);
    ls[j] = (ushort)(__float_as_uint(r) >> 16);
  }
  *reinterpret_cast<ushort8v*>(&dh[doff]) = *reinterpret_cast<ushort8v*>(hs);
  if (wantlo)
    *reinterpret_cast<ushort8v*>(&dl[doff]) = *reinterpret_cast<ushort8v*>(ls);
}

// ------- gemm_in: 64x256 tile, A bf16 + B split, bf16 out --------------------
// grid (8, 64) = 512 blocks; 4 waves, each 64x64; dynamic LDS 73728 B.
__global__ __launch_bounds__(256) void gemm_in_mfma(
    const ushort* __restrict__ Ah,
    const ushort* __restrict__ Bh, const ushort* __restrict__ Bl,
    ushort* __restrict__ C)
{
  extern __shared__ ushort smu[];
  constexpr int AOFF = 0, BHOFF = 4096, BLOFF = 20480;  // ushort offsets
  const int tid = threadIdx.x, lane = tid & 63, wid = tid >> 6;
  const int bn = blockIdx.x, bm = blockIdx.y;
  const int bm0 = bm * 64;
  const int rtA = bm0 >> 7, half = (bm0 >> 6) & 1;
  f32x4 acc[4][4];
#pragma unroll
  for (int i = 0; i < 4; ++i)
#pragma unroll
    for (int j = 0; j < 4; ++j) acc[i][j] = (f32x4){0.f, 0.f, 0.f, 0.f};
  const int rtB = wid >> 1;          // wave's B chunk half (cols wid*64)
  const int nsub = (wid & 1) * 4;

  for (int kt = 0; kt < 8; ++kt) {
    if (wid == 0) {                  // A: 8 sub-units (kk2 x msub4)
      const ushort* cb = Ah + ((size_t)(rtA * 8 + kt)) * 8192;
#pragma unroll
      for (int kk = 0; kk < 2; ++kk)
#pragma unroll
        for (int m = 0; m < 4; ++m)
          GLDS(cb + (kk * 8 + half * 4 + m) * 512 + lane * 8,
               smu + AOFF + (kk * 4 + m) * 512);
    } else if (wid == 1) {           // Bh rt0+rt1
#pragma unroll
      for (int rt = 0; rt < 2; ++rt) {
        const ushort* cb = Bh + ((size_t)((bn * 2 + rt) * 8 + kt)) * 8192;
#pragma unroll
        for (int i = 0; i < 16; ++i)
          GLDS(cb + i * 512 + lane * 8, smu + BHOFF + rt * 8192 + i * 512);
      }
    } else if (wid == 2) {           // Bl rt0+rt1
#pragma unroll
      for (int rt = 0; rt < 2; ++rt) {
        const ushort* cb = Bl + ((size_t)((bn * 2 + rt) * 8 + kt)) * 8192;
#pragma unroll
        for (int i = 0; i < 16; ++i)
          GLDS(cb + i * 512 + lane * 8, smu + BLOFF + rt * 8192 + i * 512);
      }
    }
    __syncthreads();
#pragma unroll
    for (int kk = 0; kk < 2; ++kk) {
      short8v a[4], b[4];
#pragma unroll
      for (int i = 0; i < 4; ++i)
        a[i] = *reinterpret_cast<const short8v*>(&smu[AOFF + ((kk * 4 + i) * 64 + lane) * 8]);
#pragma unroll
      for (int j = 0; j < 4; ++j)
        b[j] = *reinterpret_cast<const short8v*>(
            &smu[BHOFF + rtB * 8192 + ((kk * 8 + nsub + j) * 64 + lane) * 8]);
#pragma unroll
      for (int ms = 0; ms < 4; ++ms)
#pragma unroll
        for (int ns = 0; ns < 4; ++ns)
          acc[ms][ns] = __builtin_amdgcn_mfma_f32_16x16x32_bf16(a[ms], b[ns], acc[ms][ns], 0, 0, 0);
#pragma unroll
      for (int j = 0; j < 4; ++j)
        b[j] = *reinterpret_cast<const short8v*>(
            &smu[BLOFF + rtB * 8192 + ((kk * 8 + nsub + j) * 64 + lane) * 8]);
#pragma unroll
      for (int ms = 0; ms < 4; ++ms)
#pragma unroll
        for (int ns = 0; ns < 4; ++ns)
          acc[ms][ns] = __builtin_amdgcn_mfma_f32_16x16x32_bf16(a[ms], b[ns], acc[ms][ns], 0, 0, 0);
    }
    __syncthreads();
  }
  const int cr = lane >> 4, cc = lane & 15;
#pragma unroll
  for (int ms = 0; ms < 4; ++ms) {
    int row0 = bm0 + ms * 16 + cr * 4;
#pragma unroll
    for (int ns = 0; ns < 4; ++ns) {
      int col = bn * 256 + wid * 64 + ns * 16 + cc;
#pragma unroll
      for (int r = 0; r < 4; ++r)
        C[(size_t)(row0 + r) * 2048 + col] = bf16_rne(acc[ms][ns][r]);
    }
  }
}

// ------- gemm_out: 128x128 tile, split-K z=2, B single-bf16, f32 slices ------
__global__ __launch_bounds__(256) void gemm_out_mfma(
    const ushort* __restrict__ Ah, const ushort* __restrict__ Bh,
    float* __restrict__ P)
{
  constexpr int ASZ = 8192;
  __shared__ ushort lds[2 * ASZ];
  const int tid = threadIdx.x, lane = tid & 63, wid = tid >> 6;
  const int wm = wid >> 1, wn = wid & 1;
  const int bm = blockIdx.y, bn = blockIdx.x, z = blockIdx.z;
  f32x4 acc[4][4];
#pragma unroll
  for (int i = 0; i < 4; ++i)
#pragma unroll
    for (int j = 0; j < 4; ++j) acc[i][j] = (f32x4){0.f, 0.f, 0.f, 0.f};
  const int msel = wm * 4, nsel = wn * 4;
  for (int kt = z * 8; kt < z * 8 + 8; ++kt) {
    if (wid == 0) {
      const ushort* cb = Ah + ((size_t)(bm * 16 + kt)) * 8192;
#pragma unroll
      for (int i = 0; i < 16; ++i)
        GLDS(cb + i * 512 + lane * 8, lds + i * 512);
    } else if (wid == 1) {
      const ushort* cb = Bh + ((size_t)(bn * 16 + kt)) * 8192;
#pragma unroll
      for (int i = 0; i < 16; ++i)
        GLDS(cb + i * 512 + lane * 8, lds + ASZ + i * 512);
    }
    __syncthreads();
#pragma unroll
    for (int kk = 0; kk < 2; ++kk) {
      short8v a[4], b[4];
#pragma unroll
      for (int i = 0; i < 4; ++i) {
        a[i] = *reinterpret_cast<const short8v*>(&lds[((kk * 8 + msel + i) * 64 + lane) * 8]);
        b[i] = *reinterpret_cast<const short8v*>(&lds[ASZ + ((kk * 8 + nsel + i) * 64 + lane) * 8]);
      }
#pragma unroll
      for (int ms = 0; ms < 4; ++ms)
#pragma unroll
        for (int ns = 0; ns < 4; ++ns)
          acc[ms][ns] = __builtin_amdgcn_mfma_f32_16x16x32_bf16(a[ms], b[ns], acc[ms][ns], 0, 0, 0);
    }
    __syncthreads();
  }
  float* Pz = P + (size_t)z * BLQ * Dmodel;
  const int cr = lane >> 4, cc = lane & 15;
#pragma unroll
  for (int ms = 0; ms < 4; ++ms) {
    int row0 = bm * 128 + (msel + ms) * 16 + cr * 4;
#pragma unroll
    for (int ns = 0; ns < 4; ++ns) {
      int col = bn * 128 + (nsel + ns) * 16 + cc;
#pragma unroll
      for (int r = 0; r < 4; ++r)
        Pz[(size_t)(row0 + r) * Dmodel + col] = acc[ms][ns][r];
    }
  }
}

// ------- convxp: conv+silu + xp GEMM partial, BM=16, split-K z=2, 512 blocks -
__global__ __launch_bounds__(256) void convxp_kernel(
    const ushort* __restrict__ XZb, const float* __restrict__ cw,
    const float* __restrict__ cb,
    const ushort* __restrict__ XPh, const ushort* __restrict__ XPl,
    float* __restrict__ XC, float* __restrict__ P)
{
  constexpr int XZOFF = 0;     // 18 rows x stride 72 = 1296
  constexpr int AOFF  = 1312;  // [kk2][lane64][8] = 1024 (XOR-swizzled)
  constexpr int BHOFF = 2336;  // [kk2][msub4][64][8] = 4096
  constexpr int BLOFF = 6432;  // 4096
  __shared__ ushort smu[10528];
  const int tid = threadIdx.x, lane = tid & 63, wid = tid >> 6;
  const int cr = lane >> 4, cc = lane & 15;
  const int bm0 = blockIdx.x * 16;
  const int z = blockIdx.y;
  const int batchbase = bm0 & ~(Lseq - 1);
  f32x4 acc = (f32x4){0.f, 0.f, 0.f, 0.f};

  for (int kt = z * 8; kt < z * 8 + 8; ++kt) {
    const int kcol0 = kt * 64;
    if (wid < 2) {            // stage raw xz rows bm0-2 .. bm0+15 (18 x 64)
#pragma unroll
      for (int i = 0; i < 2; ++i) {
        int u = tid + i * 128;
        if (u < 144) {
          int r = u >> 3, c8 = u & 7;
          int grow = bm0 - 2 + r;
          ushort8v v = {};
          if (grow >= batchbase)
            v = *reinterpret_cast<const ushort8v*>(
                &XZb[(size_t)grow * 2048 + kcol0 + c8 * 8]);
          *reinterpret_cast<ushort8v*>(&smu[XZOFF + r * 72 + c8 * 8]) = v;
        }
      }
    } else {                  // stage xp B chunk halves (msub 0..3 only)
      const ushort* src = ((wid == 2) ? XPh : XPl) + (size_t)kt * 8192 + lane * 8;
      int dst0 = (wid == 2) ? BHOFF : BLOFF;
#pragma unroll
      for (int i = 0; i < 8; ++i) {
        int sidx = (i >> 2) * 8 + (i & 3);       // {0,1,2,3,8,9,10,11}
        GLDS(src + sidx * 512, smu + dst0 + i * 512);
      }
    }
    __syncthreads();
    // conv + silu: 128 units (16 rows x 8 col-groups)
    if (tid < 128) {
      int row = tid >> 3, c8 = tid & 7;
      int d0 = kcol0 + c8 * 8;
      ushort8v cur = *reinterpret_cast<ushort8v*>(&smu[XZOFF + (row + 2) * 72 + c8 * 8]);
      ushort8v pm1 = *reinterpret_cast<ushort8v*>(&smu[XZOFF + (row + 1) * 72 + c8 * 8]);
      ushort8v pm2 = *reinterpret_cast<ushort8v*>(&smu[XZOFF + (row + 0) * 72 + c8 * 8]);
      float wv[24], bv[8];
#pragma unroll
      for (int q = 0; q < 6; ++q)
        *reinterpret_cast<float4*>(&wv[q * 4]) =
            *reinterpret_cast<const float4*>(&cw[d0 * 3 + q * 4]);
      *reinterpret_cast<float4*>(&bv[0]) = *reinterpret_cast<const float4*>(&cb[d0]);
      *reinterpret_cast<float4*>(&bv[4]) = *reinterpret_cast<const float4*>(&cb[d0 + 4]);
      float os[8]; ushort hv[8];
#pragma unroll
      for (int e = 0; e < 8; ++e) {
        float a = bv[e];
        a = fmaf(bf2f(pm2[e]), wv[e * 3 + 0], a);
        a = fmaf(bf2f(pm1[e]), wv[e * 3 + 1], a);
        a = fmaf(bf2f(cur[e]), wv[e * 3 + 2], a);
        float s = a / (1.f + __expf(-a));
        os[e] = s; hv[e] = bf16_rne(s);
      }
      float* op = &XC[(size_t)(bm0 + row) * DI + d0];
      *reinterpret_cast<float4*>(op) = *reinterpret_cast<float4*>(&os[0]);
      *reinterpret_cast<float4*>(op + 4) = *reinterpret_cast<float4*>(&os[4]);
      int kk = c8 >> 2, k8 = c8 & 3;
      int idx = (kk * 64 + (row | (k8 << 4))) ^ k8;   // XOR de-conflict
      *reinterpret_cast<ushort8v*>(&smu[AOFF + idx * 8]) =
          *reinterpret_cast<ushort8v*>(hv);
    }
    __syncthreads();
#pragma unroll
    for (int kk = 0; kk < 2; ++kk) {
      int aidx = (kk * 64 + lane) ^ ((lane >> 4) & 3);
      short8v a = *reinterpret_cast<const short8v*>(&smu[AOFF + aidx * 8]);
      short8v bh = *reinterpret_cast<const short8v*>(&smu[BHOFF + ((kk * 4 + wid) * 64 + lane) * 8]);
      short8v bl = *reinterpret_cast<const short8v*>(&smu[BLOFF + ((kk * 4 + wid) * 64 + lane) * 8]);
      acc = __builtin_amdgcn_mfma_f32_16x16x32_bf16(a, bh, acc, 0, 0, 0);
      acc = __builtin_amdgcn_mfma_f32_16x16x32_bf16(a, bl, acc, 0, 0, 0);
    }
    __syncthreads();
  }
  float* Pz = P + (size_t)z * BLQ * 64;
#pragma unroll
  for (int r = 0; r < 4; ++r)
    Pz[(size_t)(bm0 + cr * 4 + r) * 64 + wid * 16 + cc] = acc[r];
}

// ---------------- xpost: reduce 2 split-K slices + dt-proj + softplus --------
__global__ __launch_bounds__(256) void xpost_kernel(
    const float* __restrict__ P, const float* __restrict__ dtw,
    const float* __restrict__ dtb, float* __restrict__ DTb,
    float* __restrict__ BCc)
{
  const int tid = threadIdx.x;
  const size_t SL = (size_t)BLQ * 64;
  if (blockIdx.y == 16) {
    int i0 = blockIdx.x * 4096 + tid;
#pragma unroll
    for (int i = 0; i < 16; ++i) {
      int idx = i0 + i * 256;
      int bt = idx >> 5, n = idx & 31;
      size_t g = (size_t)bt * 64 + 32 + n;
      BCc[idx] = P[g] + P[SL + g];
    }
    return;
  }
  const int dg = blockIdx.y, bm0 = blockIdx.x * 128;
  __shared__ float db[128][33];
  __shared__ float wt[64][33];
#pragma unroll
  for (int i = 0; i < 16; ++i) {
    int e = tid + i * 256;
    int r = e >> 5, c = e & 31;
    size_t g = (size_t)(bm0 + r) * 64 + c;
    db[r][c] = P[g] + P[SL + g];
  }
#pragma unroll
  for (int i = 0; i < 8; ++i) {
    int e = tid + i * 256;
    int r = e >> 5, c = e & 31;
    wt[r][c] = dtw[(size_t)(dg * 64 + r) * 32 + c];
  }
  __syncthreads();
  const int d_loc = tid & 63, wv = tid >> 6;
  const float bias = dtb[dg * 64 + d_loc];
#pragma unroll 4
  for (int i = 0; i < 32; ++i) {
    int r = wv + i * 4;
    float dot = 0.f;
#pragma unroll
    for (int c = 0; c < 32; ++c) dot = fmaf(db[r][c], wt[d_loc][c], dot);
    float v = dot + bias;
    DTb[(size_t)(bm0 + r) * DI + dg * 64 + d_loc] =
        (v > 15.f) ? v : log1pf(__expf(v));
  }
}

// ---------------- scan phase 1: chunk-end states + chunk dt-sums ------------
__global__ __launch_bounds__(256) void scan_p1_kernel(
    const float* __restrict__ DTb, const float* __restrict__ XC,
    const float* __restrict__ BCc, const float* __restrict__ Alog,
    float* __restrict__ HEND, float* __restrict__ DSUM)
{
  const int d = blockIdx.x * 256 + threadIdx.x;
  const int c = blockIdx.y, b = blockIdx.z;
  const int t0 = b * Lseq + c * CLEN;
  __shared__ float Bs[CLEN][16];
#pragma unroll
  for (int i = 0; i < 2; ++i) {
    int e = threadIdx.x + i * 256;
    Bs[e >> 4][e & 15] = BCc[(size_t)(t0 + (e >> 4)) * 32 + (e & 15)];
  }
  float An[16];
#pragma unroll
  for (int j = 0; j < 4; ++j) {
    float4 a = *reinterpret_cast<const float4*>(&Alog[d * 16 + j * 4]);
    An[j * 4 + 0] = -__expf(a.x); An[j * 4 + 1] = -__expf(a.y);
    An[j * 4 + 2] = -__expf(a.z); An[j * 4 + 3] = -__expf(a.w);
  }
  __syncthreads();
  float h[16] = {};
  float S = 0.f;
  for (int t = 0; t < CLEN; ++t) {
    size_t g = (size_t)(t0 + t) * DI + d;
    float dt = DTb[g], xc = XC[g];
    S += dt;
    float dtxc = dt * xc;
#pragma unroll
    for (int n = 0; n < 16; ++n)
      h[n] = fmaf(__expf(An[n] * dt), h[n], dtxc * Bs[t][n]);
  }
  size_t hb = ((size_t)(b * NCH + c) * DI + d) * 16;
#pragma unroll
  for (int j = 0; j < 4; ++j)
    *reinterpret_cast<float4*>(&HEND[hb + j * 4]) =
        *reinterpret_cast<float4*>(&h[j * 4]);
  DSUM[(size_t)(b * NCH + c) * DI + d] = S;
}

// ------- scan phase 3: in-block prefix combine + exact recompute + epilogue --
__global__ __launch_bounds__(256) void scan_p3_kernel(
    const float* __restrict__ XC, const float* __restrict__ DTb,
    const float* __restrict__ BCc, const ushort* __restrict__ XZb,
    const float* __restrict__ HEND, const float* __restrict__ DSUM,
    const float* __restrict__ Alog, const float* __restrict__ Dp,
    ushort* __restrict__ Af)
{
  const int tid = threadIdx.x;
  const int dg = blockIdx.x, c = blockIdx.y, b = blockIdx.z;
  const int d = dg * 256 + tid;
  const int t0 = b * Lseq + c * CLEN;
  __shared__ float BC[CLEN][32];
  __shared__ float ys[CLEN][264];
#pragma unroll
  for (int i = 0; i < 4; ++i) {
    int e = tid + i * 256;
    BC[e >> 5][e & 31] = BCc[(size_t)(t0 + (e >> 5)) * 32 + (e & 31)];
  }
  float An[16], h[16];
#pragma unroll
  for (int j = 0; j < 4; ++j) {
    float4 a = *reinterpret_cast<const float4*>(&Alog[d * 16 + j * 4]);
    An[j * 4 + 0] = -__expf(a.x); An[j * 4 + 1] = -__expf(a.y);
    An[j * 4 + 2] = -__expf(a.z); An[j * 4 + 3] = -__expf(a.w);
    h[j * 4 + 0] = 0.f; h[j * 4 + 1] = 0.f; h[j * 4 + 2] = 0.f; h[j * 4 + 3] = 0.f;
  }
  // prefix combine over chunks 0..c-1 (same FMA order as the old p2 kernel)
  for (int j = 0; j < c; ++j) {
    float Dc = DSUM[(size_t)(b * NCH + j) * DI + d];
    size_t hb = ((size_t)(b * NCH + j) * DI + d) * 16;
    float he[16];
#pragma unroll
    for (int q = 0; q < 4; ++q)
      *reinterpret_cast<float4*>(&he[q * 4]) =
          *reinterpret_cast<const float4*>(&HEND[hb + q * 4]);
#pragma unroll
    for (int n = 0; n < 16; ++n)
      h[n] = fmaf(__expf(An[n] * Dc), h[n], he[n]);
  }
  float Dpv = Dp[d];
  __syncthreads();
  for (int t = 0; t < CLEN; ++t) {
    size_t g = (size_t)(t0 + t) * DI + d;
    float dt = DTb[g], xc = XC[g];
    float z = bf2f(XZb[(size_t)(t0 + t) * (2 * DI) + DI + d]);
    float dtxc = dt * xc;
    float y = 0.f;
#pragma unroll
    for (int n = 0; n < 16; ++n) {
      h[n] = fmaf(__expf(An[n] * dt), h[n], dtxc * BC[t][n]);
      y = fmaf(h[n], BC[t][16 + n], y);
    }
    float sil = z / (1.f + __expf(-z));
    ys[t][tid] = (y + xc * Dpv) * sil;
  }
  __syncthreads();
#pragma unroll
  for (int i = 0; i < 4; ++i) {
    int u = tid + i * 256;
    int tt = u >> 5, j8 = u & 31;
    int row = t0 + tt;
    int kg = dg * 256 + j8 * 8;
    ushort hv[8];
#pragma unroll
    for (int e = 0; e < 8; ++e) hv[e] = bf16_rne(ys[tt][j8 * 8 + e]);
    *reinterpret_cast<ushort8v*>(&Af[frag_off(row, kg, 16)]) =
        *reinterpret_cast<ushort8v*>(hv);
  }
}

// ------- rmsnorm over 2 split-K slices; LAST=0: A-frags, LAST=1: pool partials
template<int LAST>
__global__ __launch_bounds__(256) void rmsnorm_kernel(const float* __restrict__ X,
    const float* __restrict__ W, ushort* __restrict__ Af, float* __restrict__ PP) {
  __shared__ float pr[4][512];
  int w = threadIdx.x >> 6, lane = threadIdx.x & 63;
  int row = blockIdx.x * 4 + w;
  int k = lane * 8;
  const size_t SL = (size_t)BLQ * Dmodel;
  size_t idx = (size_t)row * Dmodel + k;
  float vs[8];
#pragma unroll
  for (int h = 0; h < 2; ++h) {
    float4 a = *reinterpret_cast<const float4*>(&X[idx + h * 4]);
    float4 b = *reinterpret_cast<const float4*>(&X[SL + idx + h * 4]);
    vs[h * 4 + 0] = a.x + b.x;
    vs[h * 4 + 1] = a.y + b.y;
    vs[h * 4 + 2] = a.z + b.z;
    vs[h * 4 + 3] = a.w + b.w;
  }
  float ss = 0.f;
#pragma unroll
  for (int e = 0; e < 8; ++e) ss = fmaf(vs[e], vs[e], ss);
#pragma unroll
  for (int o = 32; o >= 1; o >>= 1) ss += __shfl_xor(ss, o);
  float sc = rsqrtf(ss * (1.f / Dmodel) + 1e-5f);
  const float* wp = W + k;
  float4 w0 = *reinterpret_cast<const float4*>(wp);
  float4 w1 = *reinterpret_cast<const float4*>(wp + 4);
  float wsv[8] = {w0.x, w0.y, w0.z, w0.w, w1.x, w1.y, w1.z, w1.w};
  float os[8];
#pragma unroll
  for (int e = 0; e < 8; ++e) os[e] = vs[e] * sc * wsv[e];
  if (LAST == 0) {
    ushort hv[8];
#pragma unroll
    for (int e = 0; e < 8; ++e) hv[e] = bf16_rne(os[e]);
    *reinterpret_cast<ushort8v*>(&Af[frag_off(row, k, 8)]) =
        *reinterpret_cast<ushort8v*>(hv);
  } else {
#pragma unroll
    for (int e = 0; e < 8; ++e) pr[w][k + e] = os[e];
    __syncthreads();
    // PP layout transposed: PP[d][block] for contiguous pool_head reads
#pragma unroll
    for (int i = 0; i < 2; ++i) {
      int d = threadIdx.x + i * 256;
      PP[(size_t)d * 1024 + blockIdx.x] =
          (pr[0][d] + pr[1][d]) + (pr[2][d] + pr[3][d]);
    }
  }
}

// ---------------- pool-final + tanh + fc head (from transposed partials) -----
__global__ __launch_bounds__(256) void pool_head_kernel(
    const float* __restrict__ PP, const float* __restrict__ fcw,
    const float* __restrict__ fcb, float* __restrict__ out) {
  int b = blockIdx.x >> 1, j = blockIdx.x & 1;
  int tid = threadIdx.x;
  float s = 0.f;
  for (int d = tid; d < Dmodel; d += 256) {
    const float* pp = PP + (size_t)d * 1024 + b * 256;
    float p = 0.f;
#pragma unroll 8
    for (int blk = 0; blk < 256; ++blk) p += pp[blk];
    s += tanhf(p * (1.f / Lseq)) * fcw[j * Dmodel + d];
  }
#pragma unroll
  for (int o = 32; o >= 1; o >>= 1) s += __shfl_xor(s, o);
  __shared__ float w[4];
  if ((tid & 63) == 0) w[tid >> 6] = s;
  __syncthreads();
  if (tid == 0) out[b * 2 + j] = w[0] + w[1] + w[2] + w[3] + fcb[j];
}

extern "C" void kernel_launch(void* const* d_in, const int* in_sizes, int n_in,
                              void* d_out, int out_size, void* d_ws, size_t ws_size,
                              hipStream_t stream) {
  const int*   x      = (const int*)d_in[0];
  const float* emb    = (const float*)d_in[1];
  const float* norm_w = (const float*)d_in[2];
  const float* in_w   = (const float*)d_in[3];
  const float* conv_w = (const float*)d_in[4];
  const float* conv_b = (const float*)d_in[5];
  const float* xp_w   = (const float*)d_in[6];
  const float* dtp_w  = (const float*)d_in[7];
  const float* dtp_b  = (const float*)d_in[8];
  const float* A_log  = (const float*)d_in[9];
  const float* Dp     = (const float*)d_in[10];
  const float* out_w  = (const float*)d_in[11];
  const float* fc_w   = (const float*)d_in[12];
  const float* fc_b   = (const float*)d_in[13];
  float* out = (float*)d_out;

  char* p = (char*)d_ws;
  auto alloc = [&](size_t bytes) { char* r = p; p += (bytes + 255) & ~255ull; return r; };
  ushort* XZb  = (ushort*)alloc((size_t)BLQ * 2 * DI * 2);        // 16 MB
  float*  XC   = (float*) alloc((size_t)BLQ * DI * 4);            // 16 MB
  float*  DTb  = (float*) alloc((size_t)BLQ * DI * 4);            // 16 MB
  float*  BCc  = (float*) alloc((size_t)BLQ * 32 * 4);            // 0.5 MB
  float*  DBCP = (float*) alloc((size_t)2 * BLQ * 64 * 4);        //  2 MB
  float*  HEND = (float*) alloc((size_t)Bsz * NCH * DI * 16 * 4); //  8 MB
  float*  DSUM = (float*) alloc((size_t)Bsz * NCH * DI * 4);      // 0.5 MB
  float*  H2P  = (float*) alloc((size_t)2 * BLQ * Dmodel * 4);    // 16 MB
  float*  PP   = (float*) alloc((size_t)Dmodel * 1024 * 4);       //  2 MB
  ushort* AhI  = (ushort*)alloc((size_t)BLQ * Dmodel * 2);        //  4 MB
  ushort* AhO  = (ushort*)alloc((size_t)BLQ * DI * 2);            //  8 MB
  ushort* WIh  = (ushort*)alloc((size_t)2 * 2048 * 512 * 2);      //  4 MB
  ushort* WIl  = (ushort*)alloc((size_t)2 * 2048 * 512 * 2);      //  4 MB
  ushort* XPh  = (ushort*)alloc((size_t)2 * 131072 * 2);          // 0.5 MB
  ushort* XPl  = (ushort*)alloc((size_t)2 * 131072 * 2);
  ushort* WOh  = (ushort*)alloc((size_t)2 * 512 * 1024 * 2);      //  2 MB

  embcvt_kernel<<<2624, 256, 0, stream>>>(x, emb, in_w, xp_w, out_w,
      AhI, WIh, WIl, XPh, XPl, WOh);

  for (int l = 0; l < NLAYERS; ++l) {
    const float* cw  = conv_w + (size_t)l * DI * 3;
    const float* cb  = conv_b + (size_t)l * DI;
    const float* dtw = dtp_w + (size_t)l * DI * RNK;
    const float* dtb = dtp_b + (size_t)l * DI;
    const float* Al  = A_log + (size_t)l * DI * NST;
    const float* dpl = Dp    + (size_t)l * DI;
    const float* nw  = norm_w + (size_t)l * Dmodel;
    const ushort* wih = WIh + (size_t)l * 2048 * 512;
    const ushort* wil = WIl + (size_t)l * 2048 * 512;
    const ushort* xph = XPh + (size_t)l * 131072;
    const ushort* xpl = XPl + (size_t)l * 131072;
    const ushort* woh = WOh + (size_t)l * 512 * 1024;

    // xz = h @ in_w^T : 64x256 tile, 512 blocks
    gemm_in_mfma<<<dim3(8, 64), 256, 73728, stream>>>(AhI, wih, wil, XZb);

    // conv+silu + xp GEMM partials (BM=16, split-K z=2, 512 blocks)
    convxp_kernel<<<dim3(BLQ / 16, 2), 256, 0, stream>>>(XZb, cw, cb, xph, xpl,
        XC, DBCP);

    // reduce partials + dt-proj + softplus + compact B/C
    xpost_kernel<<<dim3(32, 17), 256, 0, stream>>>(DBCP, dtw, dtb, DTb, BCc);

    // chunked selective scan (p2 folded into p3 as in-block prefix)
    scan_p1_kernel<<<dim3(DI / 256, NCH, Bsz), 256, 0, stream>>>(
        DTb, XC, BCc, Al, HEND, DSUM);
    scan_p3_kernel<<<dim3(DI / 256, NCH, Bsz), 256, 0, stream>>>(
        XC, DTb, BCc, XZb, HEND, DSUM, Al, dpl, AhO);

    // h2 = y @ out_w^T : split-K z=2, 256 blocks, f32 slices
    gemm_out_mfma<<<dim3(4, 32, 2), 256, 0, stream>>>(AhO, woh, H2P);

    // h = rmsnorm(slice0+slice1) -> A-frags (l=0) or pool partials (l=1)
    if (l == NLAYERS - 1)
      rmsnorm_kernel<1><<<BLQ / 4, 256, 0, stream>>>(H2P, nw, nullptr, PP);
    else
      rmsnorm_kernel<0><<<BLQ / 4, 256, 0, stream>>>(H2P, nw, AhI, nullptr);
  }

  pool_head_kernel<<<2 * Bsz, 256, 0, stream>>>(PP, fc_w, fc_b, out);
}

// Round 13
// 290.094 us; speedup vs baseline: 1.0501x; 1.0501x over previous
//
#include <hip/hip_runtime.h>
#include <math.h>

constexpr int Bsz = 4, Lseq = 1024, Dmodel = 512, NLAYERS = 2;
constexpr int DI = 1024, NST = 16, RNK = 32;
constexpr int BLQ = Bsz * Lseq;     // 4096 rows
constexpr int NCH = 32, CLEN = 32;  // chunked scan

typedef __attribute__((ext_vector_type(8))) short short8v;
typedef __attribute__((ext_vector_type(8))) unsigned short ushort8v;
typedef __attribute__((ext_vector_type(4))) float f32x4;
typedef unsigned short ushort;

__device__ inline ushort bf16_rne(float v) {
  unsigned u = __float_as_uint(v);
  u += 0x7FFFu + ((u >> 16) & 1u);
  return (ushort)(u >> 16);
}
__device__ inline float bf2f(ushort u) {
  return __uint_as_float(((unsigned)u) << 16);
}
// fragment address for element (row, k); chunk per (rt,kt): [kk(2)][msub(8)][lane(64)][8]
__device__ inline size_t frag_off(int row, int k, int KT) {
  int kt = k >> 6, kk = (k >> 5) & 1, k8 = (k >> 3) & 3;
  int lanei = (row & 15) | (k8 << 4), msub = (row >> 4) & 7, rt = row >> 7;
  return ((((size_t)(rt * KT + kt) * 2 + kk) * 8 + msub) * 64 + lanei) * 8;
}
#define GLDS(gp, lp) __builtin_amdgcn_global_load_lds( \
    (const __attribute__((address_space(1))) void*)(gp), \
    (__attribute__((address_space(3))) void*)(lp), 16, 0, 0)

// ------- embed gather + ALL weights -> bf16 fragments, one kernel ------------
// blocks: [0,1024) embed; [1024,2048) in_w; [2048,2112) xp_w; [2112,2624) out_w
__global__ __launch_bounds__(256) void embcvt_kernel(
    const int* __restrict__ x, const float* __restrict__ emb,
    const float* __restrict__ in_w, const float* __restrict__ xp_w,
    const float* __restrict__ out_w,
    ushort* __restrict__ Af,
    ushort* __restrict__ WIh, ushort* __restrict__ WIl,
    ushort* __restrict__ XPh, ushort* __restrict__ XPl,
    ushort* __restrict__ WOh)
{
  int blk = blockIdx.x;
  if (blk < 1024) {                       // embedding -> A fragments (K=512)
    int i = blk * 256 + threadIdx.x;
    int row = i >> 6, k = (i & 63) * 8;
    int tok = x[row];
    const float* src = &emb[(size_t)tok * Dmodel + k];
    float4 v0 = *reinterpret_cast<const float4*>(src);
    float4 v1 = *reinterpret_cast<const float4*>(src + 4);
    float xs[8] = {v0.x, v0.y, v0.z, v0.w, v1.x, v1.y, v1.z, v1.w};
    ushort hv[8];
#pragma unroll
    for (int e = 0; e < 8; ++e) hv[e] = bf16_rne(xs[e]);
    *reinterpret_cast<ushort8v*>(&Af[frag_off(row, k, 8)]) =
        *reinterpret_cast<ushort8v*>(hv);
    return;
  }
  const float* src; ushort *dh, *dl; size_t doff; bool wantlo = true;
  if (blk < 2048) {                       // in_w (split)
    int u = (blk - 1024) * 256 + threadIdx.x;
    int l = u >> 17, rem = u & 131071;
    int row = rem >> 6, k = (rem & 63) * 8;
    src = in_w + (size_t)l * 2048 * 512 + (size_t)row * 512 + k;
    size_t base = (size_t)l * 2048 * 512;
    dh = WIh + base; dl = WIl + base; doff = frag_off(row, k, 8);
  } else if (blk < 2112) {                // xp_w (split; 128-row padded chunks)
    int u = (blk - 2048) * 256 + threadIdx.x;
    int l = u >> 13, rem = u & 8191;
    int row = rem >> 7, k = (rem & 127) * 8;
    src = xp_w + (size_t)l * 64 * 1024 + (size_t)row * 1024 + k;
    size_t base = (size_t)l * 131072;
    dh = XPh + base; dl = XPl + base; doff = frag_off(row, k, 16);
  } else {                                // out_w (hi only)
    int u = (blk - 2112) * 256 + threadIdx.x;
    int l = u >> 16, rem = u & 65535;
    int row = rem >> 7, k = (rem & 127) * 8;
    src = out_w + (size_t)l * 512 * 1024 + (size_t)row * 1024 + k;
    size_t base = (size_t)l * 512 * 1024;
    dh = WOh + base; dl = nullptr; doff = frag_off(row, k, 16); wantlo = false;
  }
  float4 v0 = *reinterpret_cast<const float4*>(src);
  float4 v1 = *reinterpret_cast<const float4*>(src + 4);
  float xs[8] = {v0.x, v0.y, v0.z, v0.w, v1.x, v1.y, v1.z, v1.w};
  ushort hs[8], ls[8];
#pragma unroll
  for (int j = 0; j < 8; ++j) {
    unsigned u = __float_as_uint(xs[j]);
    float hf = __uint_as_float(u & 0xFFFF0000u);
    float r = xs[j] - hf;
    hs[j] = (ushort)(u >> 16);
    ls[j] = (ushort)(__float_as_uint(r) >> 16);
  }
  *reinterpret_cast<ushort8v*>(&dh[doff]) = *reinterpret_cast<ushort8v*>(hs);
  if (wantlo)
    *reinterpret_cast<ushort8v*>(&dl[doff]) = *reinterpret_cast<ushort8v*>(ls);
}

// ------- gemm_in: 64x256 tile, A bf16 + B split, bf16 out --------------------
// grid (8, 64) = 512 blocks; 4 waves, each 64x64; dynamic LDS 73728 B.
__global__ __launch_bounds__(256) void gemm_in_mfma(
    const ushort* __restrict__ Ah,
    const ushort* __restrict__ Bh, const ushort* __restrict__ Bl,
    ushort* __restrict__ C)
{
  extern __shared__ ushort smu[];
  constexpr int AOFF = 0, BHOFF = 4096, BLOFF = 20480;  // ushort offsets
  const int tid = threadIdx.x, lane = tid & 63, wid = tid >> 6;
  const int bn = blockIdx.x, bm = blockIdx.y;
  const int bm0 = bm * 64;
  const int rtA = bm0 >> 7, half = (bm0 >> 6) & 1;
  f32x4 acc[4][4];
#pragma unroll
  for (int i = 0; i < 4; ++i)
#pragma unroll
    for (int j = 0; j < 4; ++j) acc[i][j] = (f32x4){0.f, 0.f, 0.f, 0.f};
  const int rtB = wid >> 1;          // wave's B chunk half (cols wid*64)
  const int nsub = (wid & 1) * 4;

  for (int kt = 0; kt < 8; ++kt) {
    if (wid == 0) {                  // A: 8 sub-units (kk2 x msub4)
      const ushort* cb = Ah + ((size_t)(rtA * 8 + kt)) * 8192;
#pragma unroll
      for (int kk = 0; kk < 2; ++kk)
#pragma unroll
        for (int m = 0; m < 4; ++m)
          GLDS(cb + (kk * 8 + half * 4 + m) * 512 + lane * 8,
               smu + AOFF + (kk * 4 + m) * 512);
    } else if (wid == 1) {           // Bh rt0+rt1
#pragma unroll
      for (int rt = 0; rt < 2; ++rt) {
        const ushort* cb = Bh + ((size_t)((bn * 2 + rt) * 8 + kt)) * 8192;
#pragma unroll
        for (int i = 0; i < 16; ++i)
          GLDS(cb + i * 512 + lane * 8, smu + BHOFF + rt * 8192 + i * 512);
      }
    } else if (wid == 2) {           // Bl rt0+rt1
#pragma unroll
      for (int rt = 0; rt < 2; ++rt) {
        const ushort* cb = Bl + ((size_t)((bn * 2 + rt) * 8 + kt)) * 8192;
#pragma unroll
        for (int i = 0; i < 16; ++i)
          GLDS(cb + i * 512 + lane * 8, smu + BLOFF + rt * 8192 + i * 512);
      }
    }
    __syncthreads();
#pragma unroll
    for (int kk = 0; kk < 2; ++kk) {
      short8v a[4], b[4];
#pragma unroll
      for (int i = 0; i < 4; ++i)
        a[i] = *reinterpret_cast<const short8v*>(&smu[AOFF + ((kk * 4 + i) * 64 + lane) * 8]);
#pragma unroll
      for (int j = 0; j < 4; ++j)
        b[j] = *reinterpret_cast<const short8v*>(
            &smu[BHOFF + rtB * 8192 + ((kk * 8 + nsub + j) * 64 + lane) * 8]);
#pragma unroll
      for (int ms = 0; ms < 4; ++ms)
#pragma unroll
        for (int ns = 0; ns < 4; ++ns)
          acc[ms][ns] = __builtin_amdgcn_mfma_f32_16x16x32_bf16(a[ms], b[ns], acc[ms][ns], 0, 0, 0);
#pragma unroll
      for (int j = 0; j < 4; ++j)
        b[j] = *reinterpret_cast<const short8v*>(
            &smu[BLOFF + rtB * 8192 + ((kk * 8 + nsub + j) * 64 + lane) * 8]);
#pragma unroll
      for (int ms = 0; ms < 4; ++ms)
#pragma unroll
        for (int ns = 0; ns < 4; ++ns)
          acc[ms][ns] = __builtin_amdgcn_mfma_f32_16x16x32_bf16(a[ms], b[ns], acc[ms][ns], 0, 0, 0);
    }
    __syncthreads();
  }
  const int cr = lane >> 4, cc = lane & 15;
#pragma unroll
  for (int ms = 0; ms < 4; ++ms) {
    int row0 = bm0 + ms * 16 + cr * 4;
#pragma unroll
    for (int ns = 0; ns < 4; ++ns) {
      int col = bn * 256 + wid * 64 + ns * 16 + cc;
#pragma unroll
      for (int r = 0; r < 4; ++r)
        C[(size_t)(row0 + r) * 2048 + col] = bf16_rne(acc[ms][ns][r]);
    }
  }
}

// ------- gemm_out: 128x128 tile, split-K z=2, B single-bf16, f32 slices ------
__global__ __launch_bounds__(256) void gemm_out_mfma(
    const ushort* __restrict__ Ah, const ushort* __restrict__ Bh,
    float* __restrict__ P)
{
  constexpr int ASZ = 8192;
  __shared__ ushort lds[2 * ASZ];
  const int tid = threadIdx.x, lane = tid & 63, wid = tid >> 6;
  const int wm = wid >> 1, wn = wid & 1;
  const int bm = blockIdx.y, bn = blockIdx.x, z = blockIdx.z;
  f32x4 acc[4][4];
#pragma unroll
  for (int i = 0; i < 4; ++i)
#pragma unroll
    for (int j = 0; j < 4; ++j) acc[i][j] = (f32x4){0.f, 0.f, 0.f, 0.f};
  const int msel = wm * 4, nsel = wn * 4;
  for (int kt = z * 8; kt < z * 8 + 8; ++kt) {
    if (wid == 0) {
      const ushort* cb = Ah + ((size_t)(bm * 16 + kt)) * 8192;
#pragma unroll
      for (int i = 0; i < 16; ++i)
        GLDS(cb + i * 512 + lane * 8, lds + i * 512);
    } else if (wid == 1) {
      const ushort* cb = Bh + ((size_t)(bn * 16 + kt)) * 8192;
#pragma unroll
      for (int i = 0; i < 16; ++i)
        GLDS(cb + i * 512 + lane * 8, lds + ASZ + i * 512);
    }
    __syncthreads();
#pragma unroll
    for (int kk = 0; kk < 2; ++kk) {
      short8v a[4], b[4];
#pragma unroll
      for (int i = 0; i < 4; ++i) {
        a[i] = *reinterpret_cast<const short8v*>(&lds[((kk * 8 + msel + i) * 64 + lane) * 8]);
        b[i] = *reinterpret_cast<const short8v*>(&lds[ASZ + ((kk * 8 + nsel + i) * 64 + lane) * 8]);
      }
#pragma unroll
      for (int ms = 0; ms < 4; ++ms)
#pragma unroll
        for (int ns = 0; ns < 4; ++ns)
          acc[ms][ns] = __builtin_amdgcn_mfma_f32_16x16x32_bf16(a[ms], b[ns], acc[ms][ns], 0, 0, 0);
    }
    __syncthreads();
  }
  float* Pz = P + (size_t)z * BLQ * Dmodel;
  const int cr = lane >> 4, cc = lane & 15;
#pragma unroll
  for (int ms = 0; ms < 4; ++ms) {
    int row0 = bm * 128 + (msel + ms) * 16 + cr * 4;
#pragma unroll
    for (int ns = 0; ns < 4; ++ns) {
      int col = bn * 128 + (nsel + ns) * 16 + cc;
#pragma unroll
      for (int r = 0; r < 4; ++r)
        Pz[(size_t)(row0 + r) * Dmodel + col] = acc[ms][ns][r];
    }
  }
}

// ------- convxp: conv+silu + xp GEMM partial, BM=16, split-K z=2, 512 blocks -
__global__ __launch_bounds__(256) void convxp_kernel(
    const ushort* __restrict__ XZb, const float* __restrict__ cw,
    const float* __restrict__ cb,
    const ushort* __restrict__ XPh, const ushort* __restrict__ XPl,
    float* __restrict__ XC, float* __restrict__ P)
{
  constexpr int XZOFF = 0;     // 18 rows x stride 72 = 1296
  constexpr int AOFF  = 1312;  // [kk2][lane64][8] = 1024 (XOR-swizzled)
  constexpr int BHOFF = 2336;  // [kk2][msub4][64][8] = 4096
  constexpr int BLOFF = 6432;  // 4096
  __shared__ ushort smu[10528];
  const int tid = threadIdx.x, lane = tid & 63, wid = tid >> 6;
  const int cr = lane >> 4, cc = lane & 15;
  const int bm0 = blockIdx.x * 16;
  const int z = blockIdx.y;
  const int batchbase = bm0 & ~(Lseq - 1);
  f32x4 acc = (f32x4){0.f, 0.f, 0.f, 0.f};

  for (int kt = z * 8; kt < z * 8 + 8; ++kt) {
    const int kcol0 = kt * 64;
    if (wid < 2) {            // stage raw xz rows bm0-2 .. bm0+15 (18 x 64)
#pragma unroll
      for (int i = 0; i < 2; ++i) {
        int u = tid + i * 128;
        if (u < 144) {
          int r = u >> 3, c8 = u & 7;
          int grow = bm0 - 2 + r;
          ushort8v v = {};
          if (grow >= batchbase)
            v = *reinterpret_cast<const ushort8v*>(
                &XZb[(size_t)grow * 2048 + kcol0 + c8 * 8]);
          *reinterpret_cast<ushort8v*>(&smu[XZOFF + r * 72 + c8 * 8]) = v;
        }
      }
    } else {                  // stage xp B chunk halves (msub 0..3 only)
      const ushort* src = ((wid == 2) ? XPh : XPl) + (size_t)kt * 8192 + lane * 8;
      int dst0 = (wid == 2) ? BHOFF : BLOFF;
#pragma unroll
      for (int i = 0; i < 8; ++i) {
        int sidx = (i >> 2) * 8 + (i & 3);       // {0,1,2,3,8,9,10,11}
        GLDS(src + sidx * 512, smu + dst0 + i * 512);
      }
    }
    __syncthreads();
    // conv + silu: 128 units (16 rows x 8 col-groups)
    if (tid < 128) {
      int row = tid >> 3, c8 = tid & 7;
      int d0 = kcol0 + c8 * 8;
      ushort8v cur = *reinterpret_cast<ushort8v*>(&smu[XZOFF + (row + 2) * 72 + c8 * 8]);
      ushort8v pm1 = *reinterpret_cast<ushort8v*>(&smu[XZOFF + (row + 1) * 72 + c8 * 8]);
      ushort8v pm2 = *reinterpret_cast<ushort8v*>(&smu[XZOFF + (row + 0) * 72 + c8 * 8]);
      float wv[24], bv[8];
#pragma unroll
      for (int q = 0; q < 6; ++q)
        *reinterpret_cast<float4*>(&wv[q * 4]) =
            *reinterpret_cast<const float4*>(&cw[d0 * 3 + q * 4]);
      *reinterpret_cast<float4*>(&bv[0]) = *reinterpret_cast<const float4*>(&cb[d0]);
      *reinterpret_cast<float4*>(&bv[4]) = *reinterpret_cast<const float4*>(&cb[d0 + 4]);
      float os[8]; ushort hv[8];
#pragma unroll
      for (int e = 0; e < 8; ++e) {
        float a = bv[e];
        a = fmaf(bf2f(pm2[e]), wv[e * 3 + 0], a);
        a = fmaf(bf2f(pm1[e]), wv[e * 3 + 1], a);
        a = fmaf(bf2f(cur[e]), wv[e * 3 + 2], a);
        float s = a / (1.f + __expf(-a));
        os[e] = s; hv[e] = bf16_rne(s);
      }
      float* op = &XC[(size_t)(bm0 + row) * DI + d0];
      *reinterpret_cast<float4*>(op) = *reinterpret_cast<float4*>(&os[0]);
      *reinterpret_cast<float4*>(op + 4) = *reinterpret_cast<float4*>(&os[4]);
      int kk = c8 >> 2, k8 = c8 & 3;
      int idx = (kk * 64 + (row | (k8 << 4))) ^ k8;   // XOR de-conflict
      *reinterpret_cast<ushort8v*>(&smu[AOFF + idx * 8]) =
          *reinterpret_cast<ushort8v*>(hv);
    }
    __syncthreads();
#pragma unroll
    for (int kk = 0; kk < 2; ++kk) {
      int aidx = (kk * 64 + lane) ^ ((lane >> 4) & 3);
      short8v a = *reinterpret_cast<const short8v*>(&smu[AOFF + aidx * 8]);
      short8v bh = *reinterpret_cast<const short8v*>(&smu[BHOFF + ((kk * 4 + wid) * 64 + lane) * 8]);
      short8v bl = *reinterpret_cast<const short8v*>(&smu[BLOFF + ((kk * 4 + wid) * 64 + lane) * 8]);
      acc = __builtin_amdgcn_mfma_f32_16x16x32_bf16(a, bh, acc, 0, 0, 0);
      acc = __builtin_amdgcn_mfma_f32_16x16x32_bf16(a, bl, acc, 0, 0, 0);
    }
    __syncthreads();
  }
  float* Pz = P + (size_t)z * BLQ * 64;
#pragma unroll
  for (int r = 0; r < 4; ++r)
    Pz[(size_t)(bm0 + cr * 4 + r) * 64 + wid * 16 + cc] = acc[r];
}

// ---------------- xpost: reduce 2 split-K slices + dt-proj + softplus --------
__global__ __launch_bounds__(256) void xpost_kernel(
    const float* __restrict__ P, const float* __restrict__ dtw,
    const float* __restrict__ dtb, float* __restrict__ DTb,
    float* __restrict__ BCc)
{
  const int tid = threadIdx.x;
  const size_t SL = (size_t)BLQ * 64;
  if (blockIdx.y == 16) {
    int i0 = blockIdx.x * 4096 + tid;
#pragma unroll
    for (int i = 0; i < 16; ++i) {
      int idx = i0 + i * 256;
      int bt = idx >> 5, n = idx & 31;
      size_t g = (size_t)bt * 64 + 32 + n;
      BCc[idx] = P[g] + P[SL + g];
    }
    return;
  }
  const int dg = blockIdx.y, bm0 = blockIdx.x * 128;
  __shared__ float db[128][33];
  __shared__ float wt[64][33];
#pragma unroll
  for (int i = 0; i < 16; ++i) {
    int e = tid + i * 256;
    int r = e >> 5, c = e & 31;
    size_t g = (size_t)(bm0 + r) * 64 + c;
    db[r][c] = P[g] + P[SL + g];
  }
#pragma unroll
  for (int i = 0; i < 8; ++i) {
    int e = tid + i * 256;
    int r = e >> 5, c = e & 31;
    wt[r][c] = dtw[(size_t)(dg * 64 + r) * 32 + c];
  }
  __syncthreads();
  const int d_loc = tid & 63, wv = tid >> 6;
  const float bias = dtb[dg * 64 + d_loc];
#pragma unroll 4
  for (int i = 0; i < 32; ++i) {
    int r = wv + i * 4;
    float dot = 0.f;
#pragma unroll
    for (int c = 0; c < 32; ++c) dot = fmaf(db[r][c], wt[d_loc][c], dot);
    float v = dot + bias;
    DTb[(size_t)(bm0 + r) * DI + dg * 64 + d_loc] =
        (v > 15.f) ? v : log1pf(__expf(v));
  }
}

// ---------------- scan phase 1: chunk-end states + chunk dt-sums ------------
__global__ __launch_bounds__(256) void scan_p1_kernel(
    const float* __restrict__ DTb, const float* __restrict__ XC,
    const float* __restrict__ BCc, const float* __restrict__ Alog,
    float* __restrict__ HEND, float* __restrict__ DSUM)
{
  const int d = blockIdx.x * 256 + threadIdx.x;
  const int c = blockIdx.y, b = blockIdx.z;
  const int t0 = b * Lseq + c * CLEN;
  __shared__ float Bs[CLEN][16];
#pragma unroll
  for (int i = 0; i < 2; ++i) {
    int e = threadIdx.x + i * 256;
    Bs[e >> 4][e & 15] = BCc[(size_t)(t0 + (e >> 4)) * 32 + (e & 15)];
  }
  float An[16];
#pragma unroll
  for (int j = 0; j < 4; ++j) {
    float4 a = *reinterpret_cast<const float4*>(&Alog[d * 16 + j * 4]);
    An[j * 4 + 0] = -__expf(a.x); An[j * 4 + 1] = -__expf(a.y);
    An[j * 4 + 2] = -__expf(a.z); An[j * 4 + 3] = -__expf(a.w);
  }
  __syncthreads();
  float h[16] = {};
  float S = 0.f;
  for (int t = 0; t < CLEN; ++t) {
    size_t g = (size_t)(t0 + t) * DI + d;
    float dt = DTb[g], xc = XC[g];
    S += dt;
    float dtxc = dt * xc;
#pragma unroll
    for (int n = 0; n < 16; ++n)
      h[n] = fmaf(__expf(An[n] * dt), h[n], dtxc * Bs[t][n]);
  }
  size_t hb = ((size_t)(b * NCH + c) * DI + d) * 16;
#pragma unroll
  for (int j = 0; j < 4; ++j)
    *reinterpret_cast<float4*>(&HEND[hb + j * 4]) =
        *reinterpret_cast<float4*>(&h[j * 4]);
  DSUM[(size_t)(b * NCH + c) * DI + d] = S;
}

// ---------------- scan phase 2: serial chunk combine ----------------
__global__ __launch_bounds__(256) void scan_p2_kernel(
    float* __restrict__ HEND, const float* __restrict__ DSUM,
    const float* __restrict__ Alog)
{
  int id = blockIdx.x * 256 + threadIdx.x;   // (b,d,n)
  int n = id & 15, d = (id >> 4) & (DI - 1), b = id >> 14;
  float An = -__expf(Alog[d * 16 + n]);
  float hg = 0.f;
  for (int c = 0; c < NCH; ++c) {
    size_t hi = ((size_t)(b * NCH + c) * DI + d) * 16 + n;
    float hl = HEND[hi];
    float Dc = DSUM[(size_t)(b * NCH + c) * DI + d];
    HEND[hi] = hg;
    hg = fmaf(__expf(An * Dc), hg, hl);
  }
}

// ---------------- scan phase 3: exact recompute + epilogue + A-frag out -----
__global__ __launch_bounds__(256) void scan_p3_kernel(
    const float* __restrict__ XC, const float* __restrict__ DTb,
    const float* __restrict__ BCc, const ushort* __restrict__ XZb,
    const float* __restrict__ HEND, const float* __restrict__ Alog,
    const float* __restrict__ Dp, ushort* __restrict__ Af)
{
  const int tid = threadIdx.x;
  const int dg = blockIdx.x, c = blockIdx.y, b = blockIdx.z;
  const int d = dg * 256 + tid;
  const int t0 = b * Lseq + c * CLEN;
  __shared__ float BC[CLEN][32];
  __shared__ float ys[CLEN][264];
#pragma unroll
  for (int i = 0; i < 4; ++i) {
    int e = tid + i * 256;
    BC[e >> 5][e & 31] = BCc[(size_t)(t0 + (e >> 5)) * 32 + (e & 31)];
  }
  float An[16], h[16];
  size_t hb = ((size_t)(b * NCH + c) * DI + d) * 16;
#pragma unroll
  for (int j = 0; j < 4; ++j) {
    float4 a = *reinterpret_cast<const float4*>(&Alog[d * 16 + j * 4]);
    An[j * 4 + 0] = -__expf(a.x); An[j * 4 + 1] = -__expf(a.y);
    An[j * 4 + 2] = -__expf(a.z); An[j * 4 + 3] = -__expf(a.w);
    *reinterpret_cast<float4*>(&h[j * 4]) =
        *reinterpret_cast<const float4*>(&HEND[hb + j * 4]);
  }
  float Dpv = Dp[d];
  __syncthreads();
  for (int t = 0; t < CLEN; ++t) {
    size_t g = (size_t)(t0 + t) * DI + d;
    float dt = DTb[g], xc = XC[g];
    float z = bf2f(XZb[(size_t)(t0 + t) * (2 * DI) + DI + d]);
    float dtxc = dt * xc;
    float y = 0.f;
#pragma unroll
    for (int n = 0; n < 16; ++n) {
      h[n] = fmaf(__expf(An[n] * dt), h[n], dtxc * BC[t][n]);
      y = fmaf(h[n], BC[t][16 + n], y);
    }
    float sil = z / (1.f + __expf(-z));
    ys[t][tid] = (y + xc * Dpv) * sil;
  }
  __syncthreads();
#pragma unroll
  for (int i = 0; i < 4; ++i) {
    int u = tid + i * 256;
    int tt = u >> 5, j8 = u & 31;
    int row = t0 + tt;
    int kg = dg * 256 + j8 * 8;
    ushort hv[8];
#pragma unroll
    for (int e = 0; e < 8; ++e) hv[e] = bf16_rne(ys[tt][j8 * 8 + e]);
    *reinterpret_cast<ushort8v*>(&Af[frag_off(row, kg, 16)]) =
        *reinterpret_cast<ushort8v*>(hv);
  }
}

// ------- rmsnorm over 2 split-K slices; LAST=0: A-frags, LAST=1: pool partials
template<int LAST>
__global__ __launch_bounds__(256) void rmsnorm_kernel(const float* __restrict__ X,
    const float* __restrict__ W, ushort* __restrict__ Af, float* __restrict__ PP) {
  __shared__ float pr[4][512];
  int w = threadIdx.x >> 6, lane = threadIdx.x & 63;
  int row = blockIdx.x * 4 + w;
  int k = lane * 8;
  const size_t SL = (size_t)BLQ * Dmodel;
  size_t idx = (size_t)row * Dmodel + k;
  float vs[8];
#pragma unroll
  for (int h = 0; h < 2; ++h) {
    float4 a = *reinterpret_cast<const float4*>(&X[idx + h * 4]);
    float4 b = *reinterpret_cast<const float4*>(&X[SL + idx + h * 4]);
    vs[h * 4 + 0] = a.x + b.x;
    vs[h * 4 + 1] = a.y + b.y;
    vs[h * 4 + 2] = a.z + b.z;
    vs[h * 4 + 3] = a.w + b.w;
  }
  float ss = 0.f;
#pragma unroll
  for (int e = 0; e < 8; ++e) ss = fmaf(vs[e], vs[e], ss);
#pragma unroll
  for (int o = 32; o >= 1; o >>= 1) ss += __shfl_xor(ss, o);
  float sc = rsqrtf(ss * (1.f / Dmodel) + 1e-5f);
  const float* wp = W + k;
  float4 w0 = *reinterpret_cast<const float4*>(wp);
  float4 w1 = *reinterpret_cast<const float4*>(wp + 4);
  float wsv[8] = {w0.x, w0.y, w0.z, w0.w, w1.x, w1.y, w1.z, w1.w};
  float os[8];
#pragma unroll
  for (int e = 0; e < 8; ++e) os[e] = vs[e] * sc * wsv[e];
  if (LAST == 0) {
    ushort hv[8];
#pragma unroll
    for (int e = 0; e < 8; ++e) hv[e] = bf16_rne(os[e]);
    *reinterpret_cast<ushort8v*>(&Af[frag_off(row, k, 8)]) =
        *reinterpret_cast<ushort8v*>(hv);
  } else {
#pragma unroll
    for (int e = 0; e < 8; ++e) pr[w][k + e] = os[e];
    __syncthreads();
    // PP layout transposed: PP[d][block] for contiguous pool_head reads
#pragma unroll
    for (int i = 0; i < 2; ++i) {
      int d = threadIdx.x + i * 256;
      PP[(size_t)d * 1024 + blockIdx.x] =
          (pr[0][d] + pr[1][d]) + (pr[2][d] + pr[3][d]);
    }
  }
}

// ---------------- pool-final + tanh + fc head (from transposed partials) -----
__global__ __launch_bounds__(256) void pool_head_kernel(
    const float* __restrict__ PP, const float* __restrict__ fcw,
    const float* __restrict__ fcb, float* __restrict__ out) {
  int b = blockIdx.x >> 1, j = blockIdx.x & 1;
  int tid = threadIdx.x;
  float s = 0.f;
  for (int d = tid; d < Dmodel; d += 256) {
    const float* pp = PP + (size_t)d * 1024 + b * 256;
    float p = 0.f;
#pragma unroll 8
    for (int blk = 0; blk < 256; ++blk) p += pp[blk];
    s += tanhf(p * (1.f / Lseq)) * fcw[j * Dmodel + d];
  }
#pragma unroll
  for (int o = 32; o >= 1; o >>= 1) s += __shfl_xor(s, o);
  __shared__ float w[4];
  if ((tid & 63) == 0) w[tid >> 6] = s;
  __syncthreads();
  if (tid == 0) out[b * 2 + j] = w[0] + w[1] + w[2] + w[3] + fcb[j];
}

extern "C" void kernel_launch(void* const* d_in, const int* in_sizes, int n_in,
                              void* d_out, int out_size, void* d_ws, size_t ws_size,
                              hipStream_t stream) {
  const int*   x      = (const int*)d_in[0];
  const float* emb    = (const float*)d_in[1];
  const float* norm_w = (const float*)d_in[2];
  const float* in_w   = (const float*)d_in[3];
  const float* conv_w = (const float*)d_in[4];
  const float* conv_b = (const float*)d_in[5];
  const float* xp_w   = (const float*)d_in[6];
  const float* dtp_w  = (const float*)d_in[7];
  const float* dtp_b  = (const float*)d_in[8];
  const float* A_log  = (const float*)d_in[9];
  const float* Dp     = (const float*)d_in[10];
  const float* out_w  = (const float*)d_in[11];
  const float* fc_w   = (const float*)d_in[12];
  const float* fc_b   = (const float*)d_in[13];
  float* out = (float*)d_out;

  char* p = (char*)d_ws;
  auto alloc = [&](size_t bytes) { char* r = p; p += (bytes + 255) & ~255ull; return r; };
  ushort* XZb  = (ushort*)alloc((size_t)BLQ * 2 * DI * 2);        // 16 MB
  float*  XC   = (float*) alloc((size_t)BLQ * DI * 4);            // 16 MB
  float*  DTb  = (float*) alloc((size_t)BLQ * DI * 4);            // 16 MB
  float*  BCc  = (float*) alloc((size_t)BLQ * 32 * 4);            // 0.5 MB
  float*  DBCP = (float*) alloc((size_t)2 * BLQ * 64 * 4);        //  2 MB
  float*  HEND = (float*) alloc((size_t)Bsz * NCH * DI * 16 * 4); //  8 MB
  float*  DSUM = (float*) alloc((size_t)Bsz * NCH * DI * 4);      // 0.5 MB
  float*  H2P  = (float*) alloc((size_t)2 * BLQ * Dmodel * 4);    // 16 MB
  float*  PP   = (float*) alloc((size_t)Dmodel * 1024 * 4);       //  2 MB
  ushort* AhI  = (ushort*)alloc((size_t)BLQ * Dmodel * 2);        //  4 MB
  ushort* AhO  = (ushort*)alloc((size_t)BLQ * DI * 2);            //  8 MB
  ushort* WIh  = (ushort*)alloc((size_t)2 * 2048 * 512 * 2);      //  4 MB
  ushort* WIl  = (ushort*)alloc((size_t)2 * 2048 * 512 * 2);      //  4 MB
  ushort* XPh  = (ushort*)alloc((size_t)2 * 131072 * 2);          // 0.5 MB
  ushort* XPl  = (ushort*)alloc((size_t)2 * 131072 * 2);
  ushort* WOh  = (ushort*)alloc((size_t)2 * 512 * 1024 * 2);      //  2 MB

  embcvt_kernel<<<2624, 256, 0, stream>>>(x, emb, in_w, xp_w, out_w,
      AhI, WIh, WIl, XPh, XPl, WOh);

  for (int l = 0; l < NLAYERS; ++l) {
    const float* cw  = conv_w + (size_t)l * DI * 3;
    const float* cb  = conv_b + (size_t)l * DI;
    const float* dtw = dtp_w + (size_t)l * DI * RNK;
    const float* dtb = dtp_b + (size_t)l * DI;
    const float* Al  = A_log + (size_t)l * DI * NST;
    const float* dpl = Dp    + (size_t)l * DI;
    const float* nw  = norm_w + (size_t)l * Dmodel;
    const ushort* wih = WIh + (size_t)l * 2048 * 512;
    const ushort* wil = WIl + (size_t)l * 2048 * 512;
    const ushort* xph = XPh + (size_t)l * 131072;
    const ushort* xpl = XPl + (size_t)l * 131072;
    const ushort* woh = WOh + (size_t)l * 512 * 1024;

    // xz = h @ in_w^T : 64x256 tile, 512 blocks
    gemm_in_mfma<<<dim3(8, 64), 256, 73728, stream>>>(AhI, wih, wil, XZb);

    // conv+silu + xp GEMM partials (BM=16, split-K z=2, 512 blocks)
    convxp_kernel<<<dim3(BLQ / 16, 2), 256, 0, stream>>>(XZb, cw, cb, xph, xpl,
        XC, DBCP);

    // reduce partials + dt-proj + softplus + compact B/C
    xpost_kernel<<<dim3(32, 17), 256, 0, stream>>>(DBCP, dtw, dtb, DTb, BCc);

    // chunked selective scan (3 phases, R10-proven structure)
    scan_p1_kernel<<<dim3(DI / 256, NCH, Bsz), 256, 0, stream>>>(
        DTb, XC, BCc, Al, HEND, DSUM);
    scan_p2_kernel<<<Bsz * DI * NST / 256, 256, 0, stream>>>(HEND, DSUM, Al);
    scan_p3_kernel<<<dim3(DI / 256, NCH, Bsz), 256, 0, stream>>>(
        XC, DTb, BCc, XZb, HEND, Al, dpl, AhO);

    // h2 = y @ out_w^T : split-K z=2, 256 blocks, f32 slices
    gemm_out_mfma<<<dim3(4, 32, 2), 256, 0, stream>>>(AhO, woh, H2P);

    // h = rmsnorm(slice0+slice1) -> A-frags (l=0) or pool partials (l=1)
    if (l == NLAYERS - 1)
      rmsnorm_kernel<1><<<BLQ / 4, 256, 0, stream>>>(H2P, nw, nullptr, PP);
    else
      rmsnorm_kernel<0><<<BLQ / 4, 256, 0, stream>>>(H2P, nw, AhI, nullptr);
  }

  pool_head_kernel<<<2 * Bsz, 256, 0, stream>>>(PP, fc_w, fc_b, out);
}

// Round 14
// 274.467 us; speedup vs baseline: 1.1099x; 1.0569x over previous
//
#include <hip/hip_runtime.h>
#include <math.h>

constexpr int Bsz = 4, Lseq = 1024, Dmodel = 512, NLAYERS = 2;
constexpr int DI = 1024, NST = 16, RNK = 32;
constexpr int BLQ = Bsz * Lseq;     // 4096 rows
constexpr int NCH = 32, CLEN = 32;  // chunked scan

typedef __attribute__((ext_vector_type(8))) short short8v;
typedef __attribute__((ext_vector_type(8))) unsigned short ushort8v;
typedef __attribute__((ext_vector_type(4))) float f32x4;
typedef unsigned short ushort;

__device__ inline ushort bf16_rne(float v) {
  unsigned u = __float_as_uint(v);
  u += 0x7FFFu + ((u >> 16) & 1u);
  return (ushort)(u >> 16);
}
__device__ inline float bf2f(ushort u) {
  return __uint_as_float(((unsigned)u) << 16);
}
// fragment address for element (row, k); chunk per (rt,kt): [kk(2)][msub(8)][lane(64)][8]
__device__ inline size_t frag_off(int row, int k, int KT) {
  int kt = k >> 6, kk = (k >> 5) & 1, k8 = (k >> 3) & 3;
  int lanei = (row & 15) | (k8 << 4), msub = (row >> 4) & 7, rt = row >> 7;
  return ((((size_t)(rt * KT + kt) * 2 + kk) * 8 + msub) * 64 + lanei) * 8;
}
#define GLDS(gp, lp) __builtin_amdgcn_global_load_lds( \
    (const __attribute__((address_space(1))) void*)(gp), \
    (__attribute__((address_space(3))) void*)(lp), 16, 0, 0)

// ------- embed gather + ALL weights -> bf16 fragments, one kernel ------------
// blocks: [0,1024) embed; [1024,2048) in_w; [2048,2112) xp_w; [2112,2624) out_w
__global__ __launch_bounds__(256) void embcvt_kernel(
    const int* __restrict__ x, const float* __restrict__ emb,
    const float* __restrict__ in_w, const float* __restrict__ xp_w,
    const float* __restrict__ out_w,
    ushort* __restrict__ Af,
    ushort* __restrict__ WIh, ushort* __restrict__ WIl,
    ushort* __restrict__ XPh, ushort* __restrict__ XPl,
    ushort* __restrict__ WOh)
{
  int blk = blockIdx.x;
  if (blk < 1024) {                       // embedding -> A fragments (K=512)
    int i = blk * 256 + threadIdx.x;
    int row = i >> 6, k = (i & 63) * 8;
    int tok = x[row];
    const float* src = &emb[(size_t)tok * Dmodel + k];
    float4 v0 = *reinterpret_cast<const float4*>(src);
    float4 v1 = *reinterpret_cast<const float4*>(src + 4);
    float xs[8] = {v0.x, v0.y, v0.z, v0.w, v1.x, v1.y, v1.z, v1.w};
    ushort hv[8];
#pragma unroll
    for (int e = 0; e < 8; ++e) hv[e] = bf16_rne(xs[e]);
    *reinterpret_cast<ushort8v*>(&Af[frag_off(row, k, 8)]) =
        *reinterpret_cast<ushort8v*>(hv);
    return;
  }
  const float* src; ushort *dh, *dl; size_t doff; bool wantlo = true;
  if (blk < 2048) {                       // in_w (split)
    int u = (blk - 1024) * 256 + threadIdx.x;
    int l = u >> 17, rem = u & 131071;
    int row = rem >> 6, k = (rem & 63) * 8;
    src = in_w + (size_t)l * 2048 * 512 + (size_t)row * 512 + k;
    size_t base = (size_t)l * 2048 * 512;
    dh = WIh + base; dl = WIl + base; doff = frag_off(row, k, 8);
  } else if (blk < 2112) {                // xp_w (split; 128-row padded chunks)
    int u = (blk - 2048) * 256 + threadIdx.x;
    int l = u >> 13, rem = u & 8191;
    int row = rem >> 7, k = (rem & 127) * 8;
    src = xp_w + (size_t)l * 64 * 1024 + (size_t)row * 1024 + k;
    size_t base = (size_t)l * 131072;
    dh = XPh + base; dl = XPl + base; doff = frag_off(row, k, 16);
  } else {                                // out_w (hi only)
    int u = (blk - 2112) * 256 + threadIdx.x;
    int l = u >> 16, rem = u & 65535;
    int row = rem >> 7, k = (rem & 127) * 8;
    src = out_w + (size_t)l * 512 * 1024 + (size_t)row * 1024 + k;
    size_t base = (size_t)l * 512 * 1024;
    dh = WOh + base; dl = nullptr; doff = frag_off(row, k, 16); wantlo = false;
  }
  float4 v0 = *reinterpret_cast<const float4*>(src);
  float4 v1 = *reinterpret_cast<const float4*>(src + 4);
  float xs[8] = {v0.x, v0.y, v0.z, v0.w, v1.x, v1.y, v1.z, v1.w};
  ushort hs[8], ls[8];
#pragma unroll
  for (int j = 0; j < 8; ++j) {
    unsigned u = __float_as_uint(xs[j]);
    float hf = __uint_as_float(u & 0xFFFF0000u);
    float r = xs[j] - hf;
    hs[j] = (ushort)(u >> 16);
    ls[j] = (ushort)(__float_as_uint(r) >> 16);
  }
  *reinterpret_cast<ushort8v*>(&dh[doff]) = *reinterpret_cast<ushort8v*>(hs);
  if (wantlo)
    *reinterpret_cast<ushort8v*>(&dl[doff]) = *reinterpret_cast<ushort8v*>(ls);
}

// ------- gemm_in: 64x256 tile, A bf16 + B split, bf16 out --------------------
// grid (8, 64) = 512 blocks; 4 waves, each 64x64; dynamic LDS 73728 B.
__global__ __launch_bounds__(256) void gemm_in_mfma(
    const ushort* __restrict__ Ah,
    const ushort* __restrict__ Bh, const ushort* __restrict__ Bl,
    ushort* __restrict__ C)
{
  extern __shared__ ushort smu[];
  constexpr int AOFF = 0, BHOFF = 4096, BLOFF = 20480;  // ushort offsets
  const int tid = threadIdx.x, lane = tid & 63, wid = tid >> 6;
  const int bn = blockIdx.x, bm = blockIdx.y;
  const int bm0 = bm * 64;
  const int rtA = bm0 >> 7, half = (bm0 >> 6) & 1;
  f32x4 acc[4][4];
#pragma unroll
  for (int i = 0; i < 4; ++i)
#pragma unroll
    for (int j = 0; j < 4; ++j) acc[i][j] = (f32x4){0.f, 0.f, 0.f, 0.f};
  const int rtB = wid >> 1;          // wave's B chunk half (cols wid*64)
  const int nsub = (wid & 1) * 4;

  for (int kt = 0; kt < 8; ++kt) {
    if (wid == 0) {                  // A: 8 sub-units (kk2 x msub4)
      const ushort* cb = Ah + ((size_t)(rtA * 8 + kt)) * 8192;
#pragma unroll
      for (int kk = 0; kk < 2; ++kk)
#pragma unroll
        for (int m = 0; m < 4; ++m)
          GLDS(cb + (kk * 8 + half * 4 + m) * 512 + lane * 8,
               smu + AOFF + (kk * 4 + m) * 512);
    } else if (wid == 1) {           // Bh rt0+rt1
#pragma unroll
      for (int rt = 0; rt < 2; ++rt) {
        const ushort* cb = Bh + ((size_t)((bn * 2 + rt) * 8 + kt)) * 8192;
#pragma unroll
        for (int i = 0; i < 16; ++i)
          GLDS(cb + i * 512 + lane * 8, smu + BHOFF + rt * 8192 + i * 512);
      }
    } else if (wid == 2) {           // Bl rt0+rt1
#pragma unroll
      for (int rt = 0; rt < 2; ++rt) {
        const ushort* cb = Bl + ((size_t)((bn * 2 + rt) * 8 + kt)) * 8192;
#pragma unroll
        for (int i = 0; i < 16; ++i)
          GLDS(cb + i * 512 + lane * 8, smu + BLOFF + rt * 8192 + i * 512);
      }
    }
    __syncthreads();
#pragma unroll
    for (int kk = 0; kk < 2; ++kk) {
      short8v a[4], b[4];
#pragma unroll
      for (int i = 0; i < 4; ++i)
        a[i] = *reinterpret_cast<const short8v*>(&smu[AOFF + ((kk * 4 + i) * 64 + lane) * 8]);
#pragma unroll
      for (int j = 0; j < 4; ++j)
        b[j] = *reinterpret_cast<const short8v*>(
            &smu[BHOFF + rtB * 8192 + ((kk * 8 + nsub + j) * 64 + lane) * 8]);
#pragma unroll
      for (int ms = 0; ms < 4; ++ms)
#pragma unroll
        for (int ns = 0; ns < 4; ++ns)
          acc[ms][ns] = __builtin_amdgcn_mfma_f32_16x16x32_bf16(a[ms], b[ns], acc[ms][ns], 0, 0, 0);
#pragma unroll
      for (int j = 0; j < 4; ++j)
        b[j] = *reinterpret_cast<const short8v*>(
            &smu[BLOFF + rtB * 8192 + ((kk * 8 + nsub + j) * 64 + lane) * 8]);
#pragma unroll
      for (int ms = 0; ms < 4; ++ms)
#pragma unroll
        for (int ns = 0; ns < 4; ++ns)
          acc[ms][ns] = __builtin_amdgcn_mfma_f32_16x16x32_bf16(a[ms], b[ns], acc[ms][ns], 0, 0, 0);
    }
    __syncthreads();
  }
  const int cr = lane >> 4, cc = lane & 15;
#pragma unroll
  for (int ms = 0; ms < 4; ++ms) {
    int row0 = bm0 + ms * 16 + cr * 4;
#pragma unroll
    for (int ns = 0; ns < 4; ++ns) {
      int col = bn * 256 + wid * 64 + ns * 16 + cc;
#pragma unroll
      for (int r = 0; r < 4; ++r)
        C[(size_t)(row0 + r) * 2048 + col] = bf16_rne(acc[ms][ns][r]);
    }
  }
}

// ------- gemm_out: 128x128 tile, split-K z=2, B single-bf16, f32 slices ------
__global__ __launch_bounds__(256) void gemm_out_mfma(
    const ushort* __restrict__ Ah, const ushort* __restrict__ Bh,
    float* __restrict__ P)
{
  constexpr int ASZ = 8192;
  __shared__ ushort lds[2 * ASZ];
  const int tid = threadIdx.x, lane = tid & 63, wid = tid >> 6;
  const int wm = wid >> 1, wn = wid & 1;
  const int bm = blockIdx.y, bn = blockIdx.x, z = blockIdx.z;
  f32x4 acc[4][4];
#pragma unroll
  for (int i = 0; i < 4; ++i)
#pragma unroll
    for (int j = 0; j < 4; ++j) acc[i][j] = (f32x4){0.f, 0.f, 0.f, 0.f};
  const int msel = wm * 4, nsel = wn * 4;
  for (int kt = z * 8; kt < z * 8 + 8; ++kt) {
    if (wid == 0) {
      const ushort* cb = Ah + ((size_t)(bm * 16 + kt)) * 8192;
#pragma unroll
      for (int i = 0; i < 16; ++i)
        GLDS(cb + i * 512 + lane * 8, lds + i * 512);
    } else if (wid == 1) {
      const ushort* cb = Bh + ((size_t)(bn * 16 + kt)) * 8192;
#pragma unroll
      for (int i = 0; i < 16; ++i)
        GLDS(cb + i * 512 + lane * 8, lds + ASZ + i * 512);
    }
    __syncthreads();
#pragma unroll
    for (int kk = 0; kk < 2; ++kk) {
      short8v a[4], b[4];
#pragma unroll
      for (int i = 0; i < 4; ++i) {
        a[i] = *reinterpret_cast<const short8v*>(&lds[((kk * 8 + msel + i) * 64 + lane) * 8]);
        b[i] = *reinterpret_cast<const short8v*>(&lds[ASZ + ((kk * 8 + nsel + i) * 64 + lane) * 8]);
      }
#pragma unroll
      for (int ms = 0; ms < 4; ++ms)
#pragma unroll
        for (int ns = 0; ns < 4; ++ns)
          acc[ms][ns] = __builtin_amdgcn_mfma_f32_16x16x32_bf16(a[ms], b[ns], acc[ms][ns], 0, 0, 0);
    }
    __syncthreads();
  }
  float* Pz = P + (size_t)z * BLQ * Dmodel;
  const int cr = lane >> 4, cc = lane & 15;
#pragma unroll
  for (int ms = 0; ms < 4; ++ms) {
    int row0 = bm * 128 + (msel + ms) * 16 + cr * 4;
#pragma unroll
    for (int ns = 0; ns < 4; ++ns) {
      int col = bn * 128 + (nsel + ns) * 16 + cc;
#pragma unroll
      for (int r = 0; r < 4; ++r)
        Pz[(size_t)(row0 + r) * Dmodel + col] = acc[ms][ns][r];
    }
  }
}

// ------- convxp: conv+silu + xp GEMM partial, BM=16, split-K z=2, 512 blocks -
__global__ __launch_bounds__(256) void convxp_kernel(
    const ushort* __restrict__ XZb, const float* __restrict__ cw,
    const float* __restrict__ cb,
    const ushort* __restrict__ XPh, const ushort* __restrict__ XPl,
    float* __restrict__ XC, float* __restrict__ P)
{
  constexpr int XZOFF = 0;     // 18 rows x stride 72 = 1296
  constexpr int AOFF  = 1312;  // [kk2][lane64][8] = 1024 (XOR-swizzled)
  constexpr int BHOFF = 2336;  // [kk2][msub4][64][8] = 4096
  constexpr int BLOFF = 6432;  // 4096
  __shared__ ushort smu[10528];
  const int tid = threadIdx.x, lane = tid & 63, wid = tid >> 6;
  const int cr = lane >> 4, cc = lane & 15;
  const int bm0 = blockIdx.x * 16;
  const int z = blockIdx.y;
  const int batchbase = bm0 & ~(Lseq - 1);
  f32x4 acc = (f32x4){0.f, 0.f, 0.f, 0.f};

  for (int kt = z * 8; kt < z * 8 + 8; ++kt) {
    const int kcol0 = kt * 64;
    if (wid < 2) {            // stage raw xz rows bm0-2 .. bm0+15 (18 x 64)
#pragma unroll
      for (int i = 0; i < 2; ++i) {
        int u = tid + i * 128;
        if (u < 144) {
          int r = u >> 3, c8 = u & 7;
          int grow = bm0 - 2 + r;
          ushort8v v = {};
          if (grow >= batchbase)
            v = *reinterpret_cast<const ushort8v*>(
                &XZb[(size_t)grow * 2048 + kcol0 + c8 * 8]);
          *reinterpret_cast<ushort8v*>(&smu[XZOFF + r * 72 + c8 * 8]) = v;
        }
      }
    } else {                  // stage xp B chunk halves (msub 0..3 only)
      const ushort* src = ((wid == 2) ? XPh : XPl) + (size_t)kt * 8192 + lane * 8;
      int dst0 = (wid == 2) ? BHOFF : BLOFF;
#pragma unroll
      for (int i = 0; i < 8; ++i) {
        int sidx = (i >> 2) * 8 + (i & 3);       // {0,1,2,3,8,9,10,11}
        GLDS(src + sidx * 512, smu + dst0 + i * 512);
      }
    }
    __syncthreads();
    // conv + silu: 128 units (16 rows x 8 col-groups)
    if (tid < 128) {
      int row = tid >> 3, c8 = tid & 7;
      int d0 = kcol0 + c8 * 8;
      ushort8v cur = *reinterpret_cast<ushort8v*>(&smu[XZOFF + (row + 2) * 72 + c8 * 8]);
      ushort8v pm1 = *reinterpret_cast<ushort8v*>(&smu[XZOFF + (row + 1) * 72 + c8 * 8]);
      ushort8v pm2 = *reinterpret_cast<ushort8v*>(&smu[XZOFF + (row + 0) * 72 + c8 * 8]);
      float wv[24], bv[8];
#pragma unroll
      for (int q = 0; q < 6; ++q)
        *reinterpret_cast<float4*>(&wv[q * 4]) =
            *reinterpret_cast<const float4*>(&cw[d0 * 3 + q * 4]);
      *reinterpret_cast<float4*>(&bv[0]) = *reinterpret_cast<const float4*>(&cb[d0]);
      *reinterpret_cast<float4*>(&bv[4]) = *reinterpret_cast<const float4*>(&cb[d0 + 4]);
      float os[8]; ushort hv[8];
#pragma unroll
      for (int e = 0; e < 8; ++e) {
        float a = bv[e];
        a = fmaf(bf2f(pm2[e]), wv[e * 3 + 0], a);
        a = fmaf(bf2f(pm1[e]), wv[e * 3 + 1], a);
        a = fmaf(bf2f(cur[e]), wv[e * 3 + 2], a);
        float s = a / (1.f + __expf(-a));
        os[e] = s; hv[e] = bf16_rne(s);
      }
      float* op = &XC[(size_t)(bm0 + row) * DI + d0];
      *reinterpret_cast<float4*>(op) = *reinterpret_cast<float4*>(&os[0]);
      *reinterpret_cast<float4*>(op + 4) = *reinterpret_cast<float4*>(&os[4]);
      int kk = c8 >> 2, k8 = c8 & 3;
      int idx = (kk * 64 + (row | (k8 << 4))) ^ k8;   // XOR de-conflict
      *reinterpret_cast<ushort8v*>(&smu[AOFF + idx * 8]) =
          *reinterpret_cast<ushort8v*>(hv);
    }
    __syncthreads();
#pragma unroll
    for (int kk = 0; kk < 2; ++kk) {
      int aidx = (kk * 64 + lane) ^ ((lane >> 4) & 3);
      short8v a = *reinterpret_cast<const short8v*>(&smu[AOFF + aidx * 8]);
      short8v bh = *reinterpret_cast<const short8v*>(&smu[BHOFF + ((kk * 4 + wid) * 64 + lane) * 8]);
      short8v bl = *reinterpret_cast<const short8v*>(&smu[BLOFF + ((kk * 4 + wid) * 64 + lane) * 8]);
      acc = __builtin_amdgcn_mfma_f32_16x16x32_bf16(a, bh, acc, 0, 0, 0);
      acc = __builtin_amdgcn_mfma_f32_16x16x32_bf16(a, bl, acc, 0, 0, 0);
    }
    __syncthreads();
  }
  float* Pz = P + (size_t)z * BLQ * 64;
#pragma unroll
  for (int r = 0; r < 4; ++r)
    Pz[(size_t)(bm0 + cr * 4 + r) * 64 + wid * 16 + cc] = acc[r];
}

// ---------------- xpost: reduce 2 split-K slices + dt-proj + softplus --------
__global__ __launch_bounds__(256) void xpost_kernel(
    const float* __restrict__ P, const float* __restrict__ dtw,
    const float* __restrict__ dtb, float* __restrict__ DTb,
    float* __restrict__ BCc)
{
  const int tid = threadIdx.x;
  const size_t SL = (size_t)BLQ * 64;
  if (blockIdx.y == 16) {
    int i0 = blockIdx.x * 4096 + tid;
#pragma unroll
    for (int i = 0; i < 16; ++i) {
      int idx = i0 + i * 256;
      int bt = idx >> 5, n = idx & 31;
      size_t g = (size_t)bt * 64 + 32 + n;
      BCc[idx] = P[g] + P[SL + g];
    }
    return;
  }
  const int dg = blockIdx.y, bm0 = blockIdx.x * 128;
  __shared__ float db[128][33];
  __shared__ float wt[64][33];
#pragma unroll
  for (int i = 0; i < 16; ++i) {
    int e = tid + i * 256;
    int r = e >> 5, c = e & 31;
    size_t g = (size_t)(bm0 + r) * 64 + c;
    db[r][c] = P[g] + P[SL + g];
  }
#pragma unroll
  for (int i = 0; i < 8; ++i) {
    int e = tid + i * 256;
    int r = e >> 5, c = e & 31;
    wt[r][c] = dtw[(size_t)(dg * 64 + r) * 32 + c];
  }
  __syncthreads();
  const int d_loc = tid & 63, wv = tid >> 6;
  const float bias = dtb[dg * 64 + d_loc];
#pragma unroll 4
  for (int i = 0; i < 32; ++i) {
    int r = wv + i * 4;
    float dot = 0.f;
#pragma unroll
    for (int c = 0; c < 32; ++c) dot = fmaf(db[r][c], wt[d_loc][c], dot);
    float v = dot + bias;
    DTb[(size_t)(bm0 + r) * DI + dg * 64 + d_loc] =
        (v > 15.f) ? v : log1pf(__expf(v));
  }
}

// ---------------- scan phase 1: chunk-end states + chunk dt-sums ------------
__global__ __launch_bounds__(256) void scan_p1_kernel(
    const float* __restrict__ DTb, const float* __restrict__ XC,
    const float* __restrict__ BCc, const float* __restrict__ Alog,
    float* __restrict__ HEND, float* __restrict__ DSUM)
{
  const int d = blockIdx.x * 256 + threadIdx.x;
  const int c = blockIdx.y, b = blockIdx.z;
  const int t0 = b * Lseq + c * CLEN;
  __shared__ float Bs[CLEN][16];
#pragma unroll
  for (int i = 0; i < 2; ++i) {
    int e = threadIdx.x + i * 256;
    Bs[e >> 4][e & 15] = BCc[(size_t)(t0 + (e >> 4)) * 32 + (e & 15)];
  }
  float An[16];
#pragma unroll
  for (int j = 0; j < 4; ++j) {
    float4 a = *reinterpret_cast<const float4*>(&Alog[d * 16 + j * 4]);
    An[j * 4 + 0] = -__expf(a.x); An[j * 4 + 1] = -__expf(a.y);
    An[j * 4 + 2] = -__expf(a.z); An[j * 4 + 3] = -__expf(a.w);
  }
  __syncthreads();
  float h[16] = {};
  float S = 0.f;
  for (int t = 0; t < CLEN; ++t) {
    size_t g = (size_t)(t0 + t) * DI + d;
    float dt = DTb[g], xc = XC[g];
    S += dt;
    float dtxc = dt * xc;
#pragma unroll
    for (int n = 0; n < 16; ++n)
      h[n] = fmaf(__expf(An[n] * dt), h[n], dtxc * Bs[t][n]);
  }
  size_t hb = ((size_t)(b * NCH + c) * DI + d) * 16;
#pragma unroll
  for (int j = 0; j < 4; ++j)
    *reinterpret_cast<float4*>(&HEND[hb + j * 4]) =
        *reinterpret_cast<float4*>(&h[j * 4]);
  DSUM[(size_t)(b * NCH + c) * DI + d] = S;
}

// ---------------- scan phase 2: serial chunk combine ----------------
__global__ __launch_bounds__(256) void scan_p2_kernel(
    float* __restrict__ HEND, const float* __restrict__ DSUM,
    const float* __restrict__ Alog)
{
  int id = blockIdx.x * 256 + threadIdx.x;   // (b,d,n)
  int n = id & 15, d = (id >> 4) & (DI - 1), b = id >> 14;
  float An = -__expf(Alog[d * 16 + n]);
  float hg = 0.f;
  for (int c = 0; c < NCH; ++c) {
    size_t hi = ((size_t)(b * NCH + c) * DI + d) * 16 + n;
    float hl = HEND[hi];
    float Dc = DSUM[(size_t)(b * NCH + c) * DI + d];
    HEND[hi] = hg;
    hg = fmaf(__expf(An * Dc), hg, hl);
  }
}

// ---------------- scan phase 3: exact recompute + epilogue + A-frag out -----
__global__ __launch_bounds__(256) void scan_p3_kernel(
    const float* __restrict__ XC, const float* __restrict__ DTb,
    const float* __restrict__ BCc, const ushort* __restrict__ XZb,
    const float* __restrict__ HEND, const float* __restrict__ Alog,
    const float* __restrict__ Dp, ushort* __restrict__ Af)
{
  const int tid = threadIdx.x;
  const int dg = blockIdx.x, c = blockIdx.y, b = blockIdx.z;
  const int d = dg * 256 + tid;
  const int t0 = b * Lseq + c * CLEN;
  __shared__ float BC[CLEN][32];
  __shared__ float ys[CLEN][264];
#pragma unroll
  for (int i = 0; i < 4; ++i) {
    int e = tid + i * 256;
    BC[e >> 5][e & 31] = BCc[(size_t)(t0 + (e >> 5)) * 32 + (e & 31)];
  }
  float An[16], h[16];
  size_t hb = ((size_t)(b * NCH + c) * DI + d) * 16;
#pragma unroll
  for (int j = 0; j < 4; ++j) {
    float4 a = *reinterpret_cast<const float4*>(&Alog[d * 16 + j * 4]);
    An[j * 4 + 0] = -__expf(a.x); An[j * 4 + 1] = -__expf(a.y);
    An[j * 4 + 2] = -__expf(a.z); An[j * 4 + 3] = -__expf(a.w);
    *reinterpret_cast<float4*>(&h[j * 4]) =
        *reinterpret_cast<const float4*>(&HEND[hb + j * 4]);
  }
  float Dpv = Dp[d];
  __syncthreads();
  for (int t = 0; t < CLEN; ++t) {
    size_t g = (size_t)(t0 + t) * DI + d;
    float dt = DTb[g], xc = XC[g];
    float z = bf2f(XZb[(size_t)(t0 + t) * (2 * DI) + DI + d]);
    float dtxc = dt * xc;
    float y = 0.f;
#pragma unroll
    for (int n = 0; n < 16; ++n) {
      h[n] = fmaf(__expf(An[n] * dt), h[n], dtxc * BC[t][n]);
      y = fmaf(h[n], BC[t][16 + n], y);
    }
    float sil = z / (1.f + __expf(-z));
    ys[t][tid] = (y + xc * Dpv) * sil;
  }
  __syncthreads();
#pragma unroll
  for (int i = 0; i < 4; ++i) {
    int u = tid + i * 256;
    int tt = u >> 5, j8 = u & 31;
    int row = t0 + tt;
    int kg = dg * 256 + j8 * 8;
    ushort hv[8];
#pragma unroll
    for (int e = 0; e < 8; ++e) hv[e] = bf16_rne(ys[tt][j8 * 8 + e]);
    *reinterpret_cast<ushort8v*>(&Af[frag_off(row, kg, 16)]) =
        *reinterpret_cast<ushort8v*>(hv);
  }
}

// ------- rmsnorm over 2 split-K slices; LAST=0: A-frags only; LAST=1: H only -
template<int LAST>
__global__ __launch_bounds__(256) void rmsnorm_kernel(const float* __restrict__ X,
    const float* __restrict__ W, float* __restrict__ O, ushort* __restrict__ Af) {
  int row = blockIdx.x * 4 + (threadIdx.x >> 6);
  int lane = threadIdx.x & 63;
  int k = lane * 8;
  const size_t SL = (size_t)BLQ * Dmodel;
  size_t idx = (size_t)row * Dmodel + k;
  float4 a0 = *reinterpret_cast<const float4*>(&X[idx]);
  float4 a1 = *reinterpret_cast<const float4*>(&X[idx + 4]);
  float4 b0 = *reinterpret_cast<const float4*>(&X[SL + idx]);
  float4 b1 = *reinterpret_cast<const float4*>(&X[SL + idx + 4]);
  float vs[8] = {a0.x + b0.x, a0.y + b0.y, a0.z + b0.z, a0.w + b0.w,
                 a1.x + b1.x, a1.y + b1.y, a1.z + b1.z, a1.w + b1.w};
  float ss = 0.f;
#pragma unroll
  for (int e = 0; e < 8; ++e) ss = fmaf(vs[e], vs[e], ss);
#pragma unroll
  for (int o = 32; o >= 1; o >>= 1) ss += __shfl_xor(ss, o);
  float sc = rsqrtf(ss * (1.f / Dmodel) + 1e-5f);
  const float* wp = W + k;
  float4 w0 = *reinterpret_cast<const float4*>(wp);
  float4 w1 = *reinterpret_cast<const float4*>(wp + 4);
  float wsv[8] = {w0.x, w0.y, w0.z, w0.w, w1.x, w1.y, w1.z, w1.w};
  float os[8];
#pragma unroll
  for (int e = 0; e < 8; ++e) os[e] = vs[e] * sc * wsv[e];
  if (LAST == 0) {
    ushort hv[8];
#pragma unroll
    for (int e = 0; e < 8; ++e) hv[e] = bf16_rne(os[e]);
    *reinterpret_cast<ushort8v*>(&Af[frag_off(row, k, 8)]) =
        *reinterpret_cast<ushort8v*>(hv);
  } else {
    float* op = O + idx;
    *reinterpret_cast<float4*>(op) = *reinterpret_cast<float4*>(&os[0]);
    *reinterpret_cast<float4*>(op + 4) = *reinterpret_cast<float4*>(&os[4]);
  }
}

// ---------------- mean-pool partials ----------------
__global__ __launch_bounds__(256) void pool_part_kernel(const float* __restrict__ H,
    float* __restrict__ part) {
  int b = blockIdx.x, dg = blockIdx.y, tc = blockIdx.z;
  int tid = threadIdx.x;
  int d = dg * 128 + (tid & 127);
  int ph = tid >> 7;
  const float* base = H + ((size_t)(b * Lseq + tc * 128 + ph * 64)) * Dmodel + d;
  float s = 0.f;
#pragma unroll 8
  for (int t = 0; t < 64; ++t) s += base[(size_t)t * Dmodel];
  __shared__ float red[256];
  red[tid] = s; __syncthreads();
  if (ph == 0)
    part[(size_t)(b * 8 + tc) * Dmodel + d] = red[tid] + red[tid + 128];
}

// ---------------- pool-final + tanh + fc head ----------------
__global__ __launch_bounds__(256) void pool_head_kernel(
    const float* __restrict__ part, const float* __restrict__ fcw,
    const float* __restrict__ fcb, float* __restrict__ out) {
  int b = blockIdx.x >> 1, j = blockIdx.x & 1;
  int tid = threadIdx.x;
  float s = 0.f;
  for (int d = tid; d < Dmodel; d += 256) {
    float p = 0.f;
#pragma unroll
    for (int tc = 0; tc < 8; ++tc) p += part[(size_t)(b * 8 + tc) * Dmodel + d];
    s += tanhf(p * (1.f / Lseq)) * fcw[j * Dmodel + d];
  }
#pragma unroll
  for (int o = 32; o >= 1; o >>= 1) s += __shfl_xor(s, o);
  __shared__ float w[4];
  if ((tid & 63) == 0) w[tid >> 6] = s;
  __syncthreads();
  if (tid == 0) out[b * 2 + j] = w[0] + w[1] + w[2] + w[3] + fcb[j];
}

extern "C" void kernel_launch(void* const* d_in, const int* in_sizes, int n_in,
                              void* d_out, int out_size, void* d_ws, size_t ws_size,
                              hipStream_t stream) {
  const int*   x      = (const int*)d_in[0];
  const float* emb    = (const float*)d_in[1];
  const float* norm_w = (const float*)d_in[2];
  const float* in_w   = (const float*)d_in[3];
  const float* conv_w = (const float*)d_in[4];
  const float* conv_b = (const float*)d_in[5];
  const float* xp_w   = (const float*)d_in[6];
  const float* dtp_w  = (const float*)d_in[7];
  const float* dtp_b  = (const float*)d_in[8];
  const float* A_log  = (const float*)d_in[9];
  const float* Dp     = (const float*)d_in[10];
  const float* out_w  = (const float*)d_in[11];
  const float* fc_w   = (const float*)d_in[12];
  const float* fc_b   = (const float*)d_in[13];
  float* out = (float*)d_out;

  char* p = (char*)d_ws;
  auto alloc = [&](size_t bytes) { char* r = p; p += (bytes + 255) & ~255ull; return r; };
  ushort* XZb  = (ushort*)alloc((size_t)BLQ * 2 * DI * 2);        // 16 MB
  float*  XC   = (float*) alloc((size_t)BLQ * DI * 4);            // 16 MB
  float*  DTb  = (float*) alloc((size_t)BLQ * DI * 4);            // 16 MB
  float*  BCc  = (float*) alloc((size_t)BLQ * 32 * 4);            // 0.5 MB
  float*  DBCP = (float*) alloc((size_t)2 * BLQ * 64 * 4);        //  2 MB
  float*  HEND = (float*) alloc((size_t)Bsz * NCH * DI * 16 * 4); //  8 MB
  float*  DSUM = (float*) alloc((size_t)Bsz * NCH * DI * 4);      // 0.5 MB
  float*  H    = (float*) alloc((size_t)BLQ * Dmodel * 4);        //  8 MB
  float*  H2P  = (float*) alloc((size_t)2 * BLQ * Dmodel * 4);    // 16 MB
  float*  PPART= (float*) alloc((size_t)Bsz * 8 * Dmodel * 4);
  ushort* AhI  = (ushort*)alloc((size_t)BLQ * Dmodel * 2);        //  4 MB
  ushort* AhO  = (ushort*)alloc((size_t)BLQ * DI * 2);            //  8 MB
  ushort* WIh  = (ushort*)alloc((size_t)2 * 2048 * 512 * 2);      //  4 MB
  ushort* WIl  = (ushort*)alloc((size_t)2 * 2048 * 512 * 2);      //  4 MB
  ushort* XPh  = (ushort*)alloc((size_t)2 * 131072 * 2);          // 0.5 MB
  ushort* XPl  = (ushort*)alloc((size_t)2 * 131072 * 2);
  ushort* WOh  = (ushort*)alloc((size_t)2 * 512 * 1024 * 2);      //  2 MB

  embcvt_kernel<<<2624, 256, 0, stream>>>(x, emb, in_w, xp_w, out_w,
      AhI, WIh, WIl, XPh, XPl, WOh);

  for (int l = 0; l < NLAYERS; ++l) {
    const float* cw  = conv_w + (size_t)l * DI * 3;
    const float* cb  = conv_b + (size_t)l * DI;
    const float* dtw = dtp_w + (size_t)l * DI * RNK;
    const float* dtb = dtp_b + (size_t)l * DI;
    const float* Al  = A_log + (size_t)l * DI * NST;
    const float* dpl = Dp    + (size_t)l * DI;
    const float* nw  = norm_w + (size_t)l * Dmodel;
    const ushort* wih = WIh + (size_t)l * 2048 * 512;
    const ushort* wil = WIl + (size_t)l * 2048 * 512;
    const ushort* xph = XPh + (size_t)l * 131072;
    const ushort* xpl = XPl + (size_t)l * 131072;
    const ushort* woh = WOh + (size_t)l * 512 * 1024;

    // xz = h @ in_w^T : 64x256 tile, 512 blocks
    gemm_in_mfma<<<dim3(8, 64), 256, 73728, stream>>>(AhI, wih, wil, XZb);

    // conv+silu + xp GEMM partials (BM=16, split-K z=2, 512 blocks)
    convxp_kernel<<<dim3(BLQ / 16, 2), 256, 0, stream>>>(XZb, cw, cb, xph, xpl,
        XC, DBCP);

    // reduce partials + dt-proj + softplus + compact B/C
    xpost_kernel<<<dim3(32, 17), 256, 0, stream>>>(DBCP, dtw, dtb, DTb, BCc);

    // chunked selective scan (3 phases, R10-proven structure)
    scan_p1_kernel<<<dim3(DI / 256, NCH, Bsz), 256, 0, stream>>>(
        DTb, XC, BCc, Al, HEND, DSUM);
    scan_p2_kernel<<<Bsz * DI * NST / 256, 256, 0, stream>>>(HEND, DSUM, Al);
    scan_p3_kernel<<<dim3(DI / 256, NCH, Bsz), 256, 0, stream>>>(
        XC, DTb, BCc, XZb, HEND, Al, dpl, AhO);

    // h2 = y @ out_w^T : split-K z=2, 256 blocks, f32 slices
    gemm_out_mfma<<<dim3(4, 32, 2), 256, 0, stream>>>(AhO, woh, H2P);

    // h = rmsnorm(slice0+slice1) -> A-frags (l<last) or fp32 H (last)
    if (l == NLAYERS - 1)
      rmsnorm_kernel<1><<<BLQ / 4, 256, 0, stream>>>(H2P, nw, H, nullptr);
    else
      rmsnorm_kernel<0><<<BLQ / 4, 256, 0, stream>>>(H2P, nw, nullptr, AhI);
  }

  pool_part_kernel<<<dim3(Bsz, Dmodel / 128, 8), 256, 0, stream>>>(H, PPART);
  pool_head_kernel<<<2 * Bsz, 256, 0, stream>>>(PPART, fc_w, fc_b, out);
}